// Round 13
// baseline (339.667 us; speedup 1.0000x reference)
//
#include <hip/hip_runtime.h>

// Problem constants
#define LSEQ 2048
#define DMODEL 512
#define DHD 64          // head dim of the (faithful) raw view
#define SLAB (LSEQ*DHD) // 131072 elements per contiguous head slab

typedef __attribute__((ext_vector_type(8))) short short8;
typedef __attribute__((ext_vector_type(4))) float f32x4;
typedef float f4raw __attribute__((ext_vector_type(4)));   // raw clang vector (NT-store legal)
typedef _Float16 half8 __attribute__((ext_vector_type(8)));
typedef _Float16 h4_t  __attribute__((ext_vector_type(4)));

__device__ __forceinline__ short f2bf(float x) {   // round-to-nearest-even bf16
    union { float f; unsigned u; } v; v.f = x;
    unsigned r = v.u + 0x7FFF + ((v.u >> 16) & 1);
    return (short)(r >> 16);
}
__device__ __forceinline__ float bf2f(short h) {
    union { float f; unsigned u; } v; v.u = ((unsigned)(unsigned short)h) << 16;
    return v.f;
}

// direct global->LDS async copy, 16 B per lane (dest = wave-uniform base + lane*16)
#define GLOAD_LDS16(g, l) __builtin_amdgcn_global_load_lds( \
    (const __attribute__((address_space(1))) void*)(g),     \
    (__attribute__((address_space(3))) void*)(l), 16, 0, 0)

#define VMCNT0()  asm volatile("s_waitcnt vmcnt(0)" ::: "memory")
#define VMCNT2()  asm volatile("s_waitcnt vmcnt(2)" ::: "memory")
#define VMCNT4()  asm volatile("s_waitcnt vmcnt(4)" ::: "memory")
#define VMCNT6()  asm volatile("s_waitcnt vmcnt(6)" ::: "memory")
#define LGKM0()   asm volatile("s_waitcnt lgkmcnt(0)" ::: "memory")
#define BARRIER() do { __builtin_amdgcn_s_barrier(); __builtin_amdgcn_sched_barrier(0); } while (0)

// ---------------------------------------------------------------------------
// Projection GEMM: C[8192,512] = A[8192,512] @ W[512,512]^T + bias
// Internally split-f32 precision: a*w ~= ah*wh + ah*wl + al*wh (3 bf16 MFMAs).
// MODE 0: write f32 Cf.   MODE 3: write f16 C0 (round once at the end).
// ---------------------------------------------------------------------------
template<int MODE>
__global__ __launch_bounds__(256) void proj_gemm(
    const float* __restrict__ A, const float* __restrict__ W,
    const float* __restrict__ bias, float* __restrict__ Cf,
    short* __restrict__ C0)
{
    __shared__ __align__(16) short Ah[64][40], Al[64][40], Bh[64][40], Bl[64][40];

    const int tid  = threadIdx.x;
    const int lane = tid & 63, wv = tid >> 6;
    const int wm = wv >> 1, wn = wv & 1;
    const int fr = lane & 15, kg = lane >> 4;
    const int m0 = blockIdx.y * 64, n0 = blockIdx.x * 64;

    f32x4 acc[2][2];
    #pragma unroll
    for (int i = 0; i < 2; ++i)
        #pragma unroll
        for (int j = 0; j < 2; ++j) { f32x4 z = {0.f,0.f,0.f,0.f}; acc[i][j] = z; }

    const int srow = tid >> 2, sc8 = (tid & 3) << 3;

    for (int kt = 0; kt < 16; ++kt) {
        __syncthreads();
        {   // stage A/W tile, converting f32 -> hi/lo bf16
            const float* ap = A + (size_t)(m0 + srow) * DMODEL + kt*32 + sc8;
            float4 a0 = *(const float4*)ap;
            float4 a1 = *(const float4*)(ap + 4);
            float va[8] = {a0.x,a0.y,a0.z,a0.w,a1.x,a1.y,a1.z,a1.w};
            short8 h, l;
            #pragma unroll
            for (int j = 0; j < 8; ++j) { short hh = f2bf(va[j]); h[j] = hh; l[j] = f2bf(va[j] - bf2f(hh)); }
            *(short8*)&Ah[srow][sc8] = h; *(short8*)&Al[srow][sc8] = l;

            const float* wp = W + (size_t)(n0 + srow) * DMODEL + kt*32 + sc8;
            float4 b0 = *(const float4*)wp;
            float4 b1 = *(const float4*)(wp + 4);
            float vb[8] = {b0.x,b0.y,b0.z,b0.w,b1.x,b1.y,b1.z,b1.w};
            #pragma unroll
            for (int j = 0; j < 8; ++j) { short hh = f2bf(vb[j]); h[j] = hh; l[j] = f2bf(vb[j] - bf2f(hh)); }
            *(short8*)&Bh[srow][sc8] = h; *(short8*)&Bl[srow][sc8] = l;
        }
        __syncthreads();

        short8 ah[2], al[2], bh[2], bl[2];
        #pragma unroll
        for (int mf = 0; mf < 2; ++mf) {
            ah[mf] = *(short8*)&Ah[wm*32 + mf*16 + fr][kg*8];
            al[mf] = *(short8*)&Al[wm*32 + mf*16 + fr][kg*8];
        }
        #pragma unroll
        for (int nf = 0; nf < 2; ++nf) {
            bh[nf] = *(short8*)&Bh[wn*32 + nf*16 + fr][kg*8];
            bl[nf] = *(short8*)&Bl[wn*32 + nf*16 + fr][kg*8];
        }
        #pragma unroll
        for (int mf = 0; mf < 2; ++mf)
            #pragma unroll
            for (int nf = 0; nf < 2; ++nf) {
                acc[mf][nf] = __builtin_amdgcn_mfma_f32_16x16x32_bf16(ah[mf], bh[nf], acc[mf][nf], 0,0,0);
                acc[mf][nf] = __builtin_amdgcn_mfma_f32_16x16x32_bf16(ah[mf], bl[nf], acc[mf][nf], 0,0,0);
                acc[mf][nf] = __builtin_amdgcn_mfma_f32_16x16x32_bf16(al[mf], bh[nf], acc[mf][nf], 0,0,0);
            }
    }

    // epilogue: C/D layout col=lane&15, row=(lane>>4)*4+reg
    #pragma unroll
    for (int mf = 0; mf < 2; ++mf)
        #pragma unroll
        for (int nf = 0; nf < 2; ++nf) {
            const int col = n0 + wn*32 + nf*16 + fr;
            const float bv = bias[col];
            #pragma unroll
            for (int r = 0; r < 4; ++r) {
                const int row = m0 + wm*32 + mf*16 + kg*4 + r;
                const float o = acc[mf][nf][r] + bv;
                const size_t idx = (size_t)row * DMODEL + col;
                if (MODE == 0) Cf[idx] = o;
                else           ((_Float16*)C0)[idx] = (_Float16)o;
            }
        }
}

// ---------------------------------------------------------------------------
// V transpose -> FRAGMENT-MAJOR layout: vtf[head][kb][d][ks] with k = kb*16+ks.
// ---------------------------------------------------------------------------
__global__ __launch_bounds__(256) void vtransf_kernel(
    const short* __restrict__ vh, short* __restrict__ vtf)
{
    __shared__ short T[64][72];
    const int tid = threadIdx.x;
    const int s  = blockIdx.y;          // head 0..31
    const int t0 = blockIdx.x * 64;     // l-tile (4 kb blocks)
    const size_t slab = (size_t)s * SLAB;

    {   // read 64 l-rows x 64 d (coalesced 32 B / thread)
        const int r = tid >> 2, c0 = (tid & 3) << 4;
        const short* src = vh + slab + (size_t)(t0 + r) * DHD + c0;
        short8 a = *(const short8*)src;
        short8 b = *(const short8*)(src + 8);
        *(short8*)&T[r][c0]     = a;
        *(short8*)&T[r][c0 + 8] = b;
    }
    __syncthreads();
    {   // write vtf[(kb*64 + d)*16 + ks] = T[kbl*16 + ks][d]  (32 B / thread)
        const int kbl = tid >> 6, d = tid & 63;
        short8 o0, o1;
        #pragma unroll
        for (int j = 0; j < 8; ++j) { o0[j] = T[kbl*16 + j][d]; o1[j] = T[kbl*16 + 8 + j][d]; }
        short* dst = vtf + slab + ((size_t)((t0 >> 4) + kbl) * 64 + d) * 16;
        *(short8*)dst       = o0;
        *(short8*)(dst + 8) = o1;
    }
}

// ---------------------------------------------------------------------------
// Attention, one WG (512 thr / 8 waves) per (bh, PAIR of 16-row q-tiles A,B).
// SWAPPED QK^T: mfma(K, Q) -> lane holds P[k=..+kg*4+{0..3}][q=fr].
//   Phase 1A: barrier-free per-wave staged QK^T for tile A (counted vmcnt).
//   Softmax A -> pre-normalized f16 quads paA[16].
//   FUSED loop: stage+QK^T for tile B interleaved with PV+NT-store of tile A
//     -> B's staging latency hides under A's store stream.
//   Epilogue A, softmax B, phase 2B (PV+store), epilogue B.
// ---------------------------------------------------------------------------
__global__ __launch_bounds__(512, 2) void attn_kernel(
    const _Float16* __restrict__ qf, const _Float16* __restrict__ kf,
    const _Float16* __restrict__ vtf,
    float* __restrict__ attn, float* __restrict__ ctx)
{
    __shared__ __align__(16) char KBuf[65536];        // 4 x 16 KB K tile slots
    __shared__ __align__(16) _Float16 PB[2][16][136]; // 8,704 B P tile (store path)
    __shared__ float redA[8][16];
    __shared__ float mrow[16], lirow[16];

    const int tid  = threadIdx.x;
    const int lane = tid & 63, wv = tid >> 6;
    const int fr = lane & 15, kg = lane >> 4;

    // head-major remap: all 64 q-pairs of head bh land on XCD (bh&7)
    const int wg  = blockIdx.x;                    // 0..2047
    const int rem = wg & 511;
    const int q0  = (rem >> 3) << 5;               // pair base (32 rows)
    const int bh  = ((wg >> 9) << 3) + (rem & 7);  // 0..31
    const size_t slab = (size_t)bh * SLAB;

    // Q fragments for both tiles (B-operand: lane fr holds its q-row)
    half8 qaA[2], qaB[2];
    #pragma unroll
    for (int ks = 0; ks < 2; ++ks) {
        qaA[ks] = *(const half8*)(qf + slab + (size_t)(q0 + fr) * DHD + ks*32 + kg*8);
        qaB[ks] = *(const half8*)(qf + slab + (size_t)(q0 + 16 + fr) * DHD + ks*32 + kg*8);
    }

    const int srow = lane >> 3;          // staging: row within 8-row block
    const int scb  = (lane & 7) ^ srow;  // pre-swizzled global 16B col-block
    const int klo = (wv << 4) + fr;      // tile-local K row (wave-private range)
    const int sw  = fr & 7;              // klo & 7
    const float C = 8.0f * 1.44269504089f;   // SCALE=8 folded into log2e

    #define STAGE_K(TI, CUR) { \
        _Pragma("unroll") \
        for (int j = 0; j < 2; ++j) { \
            const int b = wv*2 + j; \
            GLOAD_LDS16(kf + slab + (size_t)((TI)*128 + b*8 + srow)*DHD + scb*8, \
                        KBuf + (CUR)*16384 + b*1024); \
        } }
    #define KFRAGS(IDX, K0, K1) { \
        const char* rp_ = KBuf + ((IDX) & 3)*16384 + (klo << 7); \
        K0 = *(const half8*)(rp_ + ((kg ^ sw) << 4)); \
        K1 = *(const half8*)(rp_ + (((4 + kg) ^ sw) << 4)); }

    // ================= Phase 1A: QK^T tile A, barrier-free =================
    f32x4 sA[16];
    STAGE_K(0, 0); STAGE_K(1, 1); STAGE_K(2, 2);
    #pragma unroll
    for (int i = 0; i < 16; ++i) {
        if (i + 3 < 16) STAGE_K(i + 3, (i + 3) & 3);
        if      (i <= 12) VMCNT6();
        else if (i == 13) VMCNT4();
        else if (i == 14) VMCNT2();
        else              VMCNT0();
        half8 kb0, kb1; KFRAGS(i, kb0, kb1);
        f32x4 a = {0.f,0.f,0.f,0.f};
        a = __builtin_amdgcn_mfma_f32_16x16x32_f16(kb0, qaA[0], a, 0,0,0);
        a = __builtin_amdgcn_mfma_f32_16x16x32_f16(kb1, qaA[1], a, 0,0,0);
        sA[i] = a;
    }

    // ================= softmax A -> paA (normalized f16 quads) ============
    h4_t paA[16];
    {
        f32x4 mx = sA[0];
        #pragma unroll
        for (int i = 1; i < 16; ++i) {
            mx.x = fmaxf(mx.x, sA[i].x); mx.y = fmaxf(mx.y, sA[i].y);
            mx.z = fmaxf(mx.z, sA[i].z); mx.w = fmaxf(mx.w, sA[i].w);
        }
        float m = fmaxf(fmaxf(mx.x, mx.y), fmaxf(mx.z, mx.w));
        m = fmaxf(m, __shfl_xor(m, 16));
        m = fmaxf(m, __shfl_xor(m, 32));
        if (lane < 16) redA[wv][lane] = m;
        __syncthreads();
        if (tid < 16) {
            float mm = redA[0][tid];
            #pragma unroll
            for (int w = 1; w < 8; ++w) mm = fmaxf(mm, redA[w][tid]);
            mrow[tid] = mm;
        }
        __syncthreads();
        m = mrow[fr];

        float sum = 0.f;
        #pragma unroll
        for (int i = 0; i < 16; ++i) {
            f32x4 p;
            p.x = exp2f((sA[i].x - m) * C);
            p.y = exp2f((sA[i].y - m) * C);
            p.z = exp2f((sA[i].z - m) * C);
            p.w = exp2f((sA[i].w - m) * C);
            sA[i] = p;
            sum += (p.x + p.y) + (p.z + p.w);
        }
        sum += __shfl_xor(sum, 16);
        sum += __shfl_xor(sum, 32);
        if (lane < 16) redA[wv][lane] = sum;
        __syncthreads();
        if (tid < 16) {
            float l = 0.f;
            #pragma unroll
            for (int w = 0; w < 8; ++w) l += redA[w][tid];
            lirow[tid] = 1.0f / l;
        }
        __syncthreads();
        const float li = lirow[fr];
        #pragma unroll
        for (int i = 0; i < 16; ++i) {
            paA[i][0] = (_Float16)(sA[i].x * li);
            paA[i][1] = (_Float16)(sA[i].y * li);
            paA[i][2] = (_Float16)(sA[i].z * li);
            paA[i][3] = (_Float16)(sA[i].w * li);
        }
    }

    // common phase-2 state
    f32x4 acc[4];
    #pragma unroll
    for (int db = 0; db < 4; ++db) { f32x4 z = {0.f,0.f,0.f,0.f}; acc[db] = z; }
    const _Float16* vfb = vtf + slab;        // fragment-major V
    const int sq = tid >> 5, sc = tid & 31;  // store mapping: row q, 4-col chunk
    float* abaseA = attn + ((size_t)bh * LSEQ + q0 + sq) * LSEQ + (sc << 2);
    float* abaseB = abaseA + (size_t)16 * LSEQ;

    // ====== FUSED loop: stage+QK^T (B)  ||  PV + NT-store (A) ======
    f32x4 sB[16];
    int cur = 0;
    STAGE_K(0, 0); STAGE_K(1, 1); STAGE_K(2, 2);
    #pragma unroll
    for (int t = 0; t < 16; ++t) {
        if (t + 3 < 16) STAGE_K(t + 3, (t + 3) & 3);
        if      (t <= 12) VMCNT6();
        else if (t == 13) VMCNT4();
        else if (t == 14) VMCNT2();
        else              VMCNT0();
        half8 kb0, kb1; KFRAGS(t, kb0, kb1);
        f32x4 a = {0.f,0.f,0.f,0.f};
        a = __builtin_amdgcn_mfma_f32_16x16x32_f16(kb0, qaB[0], a, 0,0,0);
        a = __builtin_amdgcn_mfma_f32_16x16x32_f16(kb1, qaB[1], a, 0,0,0);
        sB[t] = a;

        // --- phase-2A step t ---
        h4_t pw = paA[t];
        *(h4_t*)&PB[cur][fr][(wv << 4) + (kg << 2)] = pw;
        const _Float16* vb = vfb + ((size_t)(t*8 + wv) << 10) + (fr << 4) + (kg << 2);
        #pragma unroll
        for (int db = 0; db < 4; ++db) {
            h4_t va = *(const h4_t*)(vb + db*256);
            acc[db] = __builtin_amdgcn_mfma_f32_16x16x16f16(va, pw, acc[db], 0,0,0);
        }
        LGKM0();
        BARRIER();
        h4_t pr = *(const h4_t*)&PB[cur][sq][sc << 2];
        f4raw o = { (float)pr[0], (float)pr[1], (float)pr[2], (float)pr[3] };
        __builtin_nontemporal_store(o, (f4raw*)(abaseA + (size_t)t * 128));
        cur ^= 1;
    }

    // ================= epilogue A: ctx rows q0..q0+15 ======================
    __syncthreads();
    {
        float* pt = (float*)KBuf;            // [8][16][64]
        #pragma unroll
        for (int db = 0; db < 4; ++db) {
            float4 o = { acc[db].x, acc[db].y, acc[db].z, acc[db].w };
            *(float4*)(pt + wv*1024 + fr*64 + db*16 + (kg << 2)) = o;
        }
    }
    __syncthreads();
    {
        float* pt = (float*)KBuf;
        const int e = tid << 1;              // 512 thr x 2 floats = 16x64
        const int q = e >> 6, d = e & 63;
        float2 r2 = {0.f, 0.f};
        #pragma unroll
        for (int w = 0; w < 8; ++w) {
            float2 t2 = *(float2*)(pt + w*1024 + q*64 + d);
            r2.x += t2.x; r2.y += t2.y;
        }
        *(float2*)(ctx + slab + (size_t)(q0 + q) * DHD + d) = r2;
    }
    __syncthreads();

    // ================= softmax B -> paB ====================================
    h4_t paB[16];
    {
        f32x4 mx = sB[0];
        #pragma unroll
        for (int i = 1; i < 16; ++i) {
            mx.x = fmaxf(mx.x, sB[i].x); mx.y = fmaxf(mx.y, sB[i].y);
            mx.z = fmaxf(mx.z, sB[i].z); mx.w = fmaxf(mx.w, sB[i].w);
        }
        float m = fmaxf(fmaxf(mx.x, mx.y), fmaxf(mx.z, mx.w));
        m = fmaxf(m, __shfl_xor(m, 16));
        m = fmaxf(m, __shfl_xor(m, 32));
        if (lane < 16) redA[wv][lane] = m;
        __syncthreads();
        if (tid < 16) {
            float mm = redA[0][tid];
            #pragma unroll
            for (int w = 1; w < 8; ++w) mm = fmaxf(mm, redA[w][tid]);
            mrow[tid] = mm;
        }
        __syncthreads();
        m = mrow[fr];

        float sum = 0.f;
        #pragma unroll
        for (int i = 0; i < 16; ++i) {
            f32x4 p;
            p.x = exp2f((sB[i].x - m) * C);
            p.y = exp2f((sB[i].y - m) * C);
            p.z = exp2f((sB[i].z - m) * C);
            p.w = exp2f((sB[i].w - m) * C);
            sB[i] = p;
            sum += (p.x + p.y) + (p.z + p.w);
        }
        sum += __shfl_xor(sum, 16);
        sum += __shfl_xor(sum, 32);
        if (lane < 16) redA[wv][lane] = sum;
        __syncthreads();
        if (tid < 16) {
            float l = 0.f;
            #pragma unroll
            for (int w = 0; w < 8; ++w) l += redA[w][tid];
            lirow[tid] = 1.0f / l;
        }
        __syncthreads();
        const float li = lirow[fr];
        #pragma unroll
        for (int i = 0; i < 16; ++i) {
            paB[i][0] = (_Float16)(sB[i].x * li);
            paB[i][1] = (_Float16)(sB[i].y * li);
            paB[i][2] = (_Float16)(sB[i].z * li);
            paB[i][3] = (_Float16)(sB[i].w * li);
        }
    }

    // ================= phase 2B: PV + NT-store tile B ======================
    #pragma unroll
    for (int db = 0; db < 4; ++db) { f32x4 z = {0.f,0.f,0.f,0.f}; acc[db] = z; }
    #pragma unroll
    for (int t = 0; t < 16; ++t) {
        h4_t pw = paB[t];
        *(h4_t*)&PB[cur][fr][(wv << 4) + (kg << 2)] = pw;
        const _Float16* vb = vfb + ((size_t)(t*8 + wv) << 10) + (fr << 4) + (kg << 2);
        #pragma unroll
        for (int db = 0; db < 4; ++db) {
            h4_t va = *(const h4_t*)(vb + db*256);
            acc[db] = __builtin_amdgcn_mfma_f32_16x16x16f16(va, pw, acc[db], 0,0,0);
        }
        LGKM0();
        BARRIER();
        h4_t pr = *(const h4_t*)&PB[cur][sq][sc << 2];
        f4raw o = { (float)pr[0], (float)pr[1], (float)pr[2], (float)pr[3] };
        __builtin_nontemporal_store(o, (f4raw*)(abaseB + (size_t)t * 128));
        cur ^= 1;
    }

    // ================= epilogue B: ctx rows q0+16..q0+31 ===================
    __syncthreads();
    {
        float* pt = (float*)KBuf;
        #pragma unroll
        for (int db = 0; db < 4; ++db) {
            float4 o = { acc[db].x, acc[db].y, acc[db].z, acc[db].w };
            *(float4*)(pt + wv*1024 + fr*64 + db*16 + (kg << 2)) = o;
        }
    }
    __syncthreads();
    {
        float* pt = (float*)KBuf;
        const int e = tid << 1;
        const int q = e >> 6, d = e & 63;
        float2 r2 = {0.f, 0.f};
        #pragma unroll
        for (int w = 0; w < 8; ++w) {
            float2 t2 = *(float2*)(pt + w*1024 + q*64 + d);
            r2.x += t2.x; r2.y += t2.y;
        }
        *(float2*)(ctx + slab + (size_t)(q0 + 16 + q) * DHD + d) = r2;
    }
    #undef STAGE_K
    #undef KFRAGS
}

// ---------------------------------------------------------------------------
// Residual + LayerNorm: out = LN(resid + x) * gamma + beta, one row per block
// ---------------------------------------------------------------------------
__global__ __launch_bounds__(128) void ln_kernel(
    const float* __restrict__ resid, const float* __restrict__ x,
    const float* __restrict__ gamma, const float* __restrict__ beta,
    float* __restrict__ out)
{
    const int row = blockIdx.x;
    const int tid = threadIdx.x;
    const size_t base = (size_t)row * DMODEL + tid*4;

    float4 v = *(const float4*)(x + base);
    float4 rq = *(const float4*)(resid + base);
    v.x += rq.x; v.y += rq.y; v.z += rq.z; v.w += rq.w;

    float s  = v.x + v.y + v.z + v.w;
    float ss = v.x*v.x + v.y*v.y + v.z*v.z + v.w*v.w;
    #pragma unroll
    for (int d = 1; d < 64; d <<= 1) { s += __shfl_xor(s, d); ss += __shfl_xor(ss, d); }

    __shared__ float red[2][2];
    const int wv = tid >> 6;
    if ((tid & 63) == 0) { red[wv][0] = s; red[wv][1] = ss; }
    __syncthreads();
    s  = red[0][0] + red[1][0];
    ss = red[0][1] + red[1][1];

    const float mu  = s * (1.0f/512.0f);
    const float var = ss * (1.0f/512.0f) - mu*mu;
    const float rs  = rsqrtf(var + 1e-5f);

    float4 g = *(const float4*)(gamma + tid*4);
    float4 b = *(const float4*)(beta + tid*4);
    float4 o;
    o.x = (v.x - mu) * rs * g.x + b.x;
    o.y = (v.y - mu) * rs * g.y + b.y;
    o.z = (v.z - mu) * rs * g.z + b.z;
    o.w = (v.w - mu) * rs * g.w + b.w;
    *(float4*)(out + base) = o;
}

// ---------------------------------------------------------------------------
extern "C" void kernel_launch(void* const* d_in, const int* in_sizes, int n_in,
                              void* d_out, int out_size, void* d_ws, size_t ws_size,
                              hipStream_t stream)
{
    const float* query = (const float*)d_in[0];
    const float* key   = (const float*)d_in[1];
    const float* value = (const float*)d_in[2];
    const float* Wq = (const float*)d_in[3];
    const float* bq = (const float*)d_in[4];
    const float* Wk = (const float*)d_in[5];
    const float* bk = (const float*)d_in[6];
    const float* Wv = (const float*)d_in[7];
    const float* bv = (const float*)d_in[8];
    const float* Wo = (const float*)d_in[9];
    const float* bo = (const float*)d_in[10];
    const float* gamma = (const float*)d_in[11];
    const float* beta  = (const float*)d_in[12];

    float* out  = (float*)d_out;            // [B,L,D] = 4,194,304 f32
    float* attn = out + 4194304;            // [32,2048,2048] f32

    const size_t NTOK = (size_t)8192 * 512; // 4,194,304 elements
    short* qv = (short*)d_ws;               // f16 projected tensors
    short* kv = qv + NTOK;
    short* vf = kv + NTOK;
    short* vtf = vf + NTOK;                 // fragment-major V^T per head
    // obuf aliases qv/kv (dead after attn_kernel); ws requirement = 32 MB
    float* obuf = (float*)d_ws;

    dim3 pgrid(8, 128), pblk(256);
    proj_gemm<3><<<pgrid, pblk, 0, stream>>>(query, Wq, bq, nullptr, qv);
    proj_gemm<3><<<pgrid, pblk, 0, stream>>>(key,   Wk, bk, nullptr, kv);
    proj_gemm<3><<<pgrid, pblk, 0, stream>>>(value, Wv, bv, nullptr, vf);

    vtransf_kernel<<<dim3(32, 32), 256, 0, stream>>>(vf, vtf);

    attn_kernel<<<2048, 512, 0, stream>>>((const _Float16*)qv, (const _Float16*)kv,
                                          (const _Float16*)vtf, attn, out /*ctx*/);

    proj_gemm<0><<<pgrid, pblk, 0, stream>>>(out /*ctx*/, Wo, bo, obuf, nullptr);
    ln_kernel<<<8192, 128, 0, stream>>>(query, obuf, gamma, beta, out);
}

// Round 14
// 330.524 us; speedup vs baseline: 1.0277x; 1.0277x over previous
//
#include <hip/hip_runtime.h>

// Problem constants
#define LSEQ 2048
#define DMODEL 512
#define DHD 64          // head dim of the (faithful) raw view
#define SLAB (LSEQ*DHD) // 131072 elements per contiguous head slab

typedef __attribute__((ext_vector_type(8))) short short8;
typedef __attribute__((ext_vector_type(4))) float f32x4;
typedef float f4raw __attribute__((ext_vector_type(4)));   // raw clang vector (NT-store legal)
typedef _Float16 half8 __attribute__((ext_vector_type(8)));
typedef _Float16 h4_t  __attribute__((ext_vector_type(4)));

__device__ __forceinline__ short f2bf(float x) {   // round-to-nearest-even bf16
    union { float f; unsigned u; } v; v.f = x;
    unsigned r = v.u + 0x7FFF + ((v.u >> 16) & 1);
    return (short)(r >> 16);
}
__device__ __forceinline__ float bf2f(short h) {
    union { float f; unsigned u; } v; v.u = ((unsigned)(unsigned short)h) << 16;
    return v.f;
}

// direct global->LDS async copy, 16 B per lane (dest = wave-uniform base + lane*16)
#define GLOAD_LDS16(g, l) __builtin_amdgcn_global_load_lds( \
    (const __attribute__((address_space(1))) void*)(g),     \
    (__attribute__((address_space(3))) void*)(l), 16, 0, 0)

#define VMCNT0()  asm volatile("s_waitcnt vmcnt(0)" ::: "memory")
#define VMCNT2()  asm volatile("s_waitcnt vmcnt(2)" ::: "memory")
#define VMCNT4()  asm volatile("s_waitcnt vmcnt(4)" ::: "memory")
#define VMCNT6()  asm volatile("s_waitcnt vmcnt(6)" ::: "memory")
#define LGKM0()   asm volatile("s_waitcnt lgkmcnt(0)" ::: "memory")
#define BARRIER() do { __builtin_amdgcn_s_barrier(); __builtin_amdgcn_sched_barrier(0); } while (0)

// ---------------------------------------------------------------------------
// Projection GEMM: C[8192,512] = A[8192,512] @ W[512,512]^T + bias
// Internally split-f32 precision: a*w ~= ah*wh + ah*wl + al*wh (3 bf16 MFMAs).
// MODE 0: write f32 Cf.   MODE 3: write f16 C0 (round once at the end).
// ---------------------------------------------------------------------------
template<int MODE>
__global__ __launch_bounds__(256) void proj_gemm(
    const float* __restrict__ A, const float* __restrict__ W,
    const float* __restrict__ bias, float* __restrict__ Cf,
    short* __restrict__ C0)
{
    __shared__ __align__(16) short Ah[64][40], Al[64][40], Bh[64][40], Bl[64][40];

    const int tid  = threadIdx.x;
    const int lane = tid & 63, wv = tid >> 6;
    const int wm = wv >> 1, wn = wv & 1;
    const int fr = lane & 15, kg = lane >> 4;
    const int m0 = blockIdx.y * 64, n0 = blockIdx.x * 64;

    f32x4 acc[2][2];
    #pragma unroll
    for (int i = 0; i < 2; ++i)
        #pragma unroll
        for (int j = 0; j < 2; ++j) { f32x4 z = {0.f,0.f,0.f,0.f}; acc[i][j] = z; }

    const int srow = tid >> 2, sc8 = (tid & 3) << 3;

    for (int kt = 0; kt < 16; ++kt) {
        __syncthreads();
        {   // stage A/W tile, converting f32 -> hi/lo bf16
            const float* ap = A + (size_t)(m0 + srow) * DMODEL + kt*32 + sc8;
            float4 a0 = *(const float4*)ap;
            float4 a1 = *(const float4*)(ap + 4);
            float va[8] = {a0.x,a0.y,a0.z,a0.w,a1.x,a1.y,a1.z,a1.w};
            short8 h, l;
            #pragma unroll
            for (int j = 0; j < 8; ++j) { short hh = f2bf(va[j]); h[j] = hh; l[j] = f2bf(va[j] - bf2f(hh)); }
            *(short8*)&Ah[srow][sc8] = h; *(short8*)&Al[srow][sc8] = l;

            const float* wp = W + (size_t)(n0 + srow) * DMODEL + kt*32 + sc8;
            float4 b0 = *(const float4*)wp;
            float4 b1 = *(const float4*)(wp + 4);
            float vb[8] = {b0.x,b0.y,b0.z,b0.w,b1.x,b1.y,b1.z,b1.w};
            #pragma unroll
            for (int j = 0; j < 8; ++j) { short hh = f2bf(vb[j]); h[j] = hh; l[j] = f2bf(vb[j] - bf2f(hh)); }
            *(short8*)&Bh[srow][sc8] = h; *(short8*)&Bl[srow][sc8] = l;
        }
        __syncthreads();

        short8 ah[2], al[2], bh[2], bl[2];
        #pragma unroll
        for (int mf = 0; mf < 2; ++mf) {
            ah[mf] = *(short8*)&Ah[wm*32 + mf*16 + fr][kg*8];
            al[mf] = *(short8*)&Al[wm*32 + mf*16 + fr][kg*8];
        }
        #pragma unroll
        for (int nf = 0; nf < 2; ++nf) {
            bh[nf] = *(short8*)&Bh[wn*32 + nf*16 + fr][kg*8];
            bl[nf] = *(short8*)&Bl[wn*32 + nf*16 + fr][kg*8];
        }
        #pragma unroll
        for (int mf = 0; mf < 2; ++mf)
            #pragma unroll
            for (int nf = 0; nf < 2; ++nf) {
                acc[mf][nf] = __builtin_amdgcn_mfma_f32_16x16x32_bf16(ah[mf], bh[nf], acc[mf][nf], 0,0,0);
                acc[mf][nf] = __builtin_amdgcn_mfma_f32_16x16x32_bf16(ah[mf], bl[nf], acc[mf][nf], 0,0,0);
                acc[mf][nf] = __builtin_amdgcn_mfma_f32_16x16x32_bf16(al[mf], bh[nf], acc[mf][nf], 0,0,0);
            }
    }

    // epilogue: C/D layout col=lane&15, row=(lane>>4)*4+reg
    #pragma unroll
    for (int mf = 0; mf < 2; ++mf)
        #pragma unroll
        for (int nf = 0; nf < 2; ++nf) {
            const int col = n0 + wn*32 + nf*16 + fr;
            const float bv = bias[col];
            #pragma unroll
            for (int r = 0; r < 4; ++r) {
                const int row = m0 + wm*32 + mf*16 + kg*4 + r;
                const float o = acc[mf][nf][r] + bv;
                const size_t idx = (size_t)row * DMODEL + col;
                if (MODE == 0) Cf[idx] = o;
                else           ((_Float16*)C0)[idx] = (_Float16)o;
            }
        }
}

// ---------------------------------------------------------------------------
// V transpose -> FRAGMENT-MAJOR layout: vtf[head][kb][d][ks] with k = kb*16+ks.
// ---------------------------------------------------------------------------
__global__ __launch_bounds__(256) void vtransf_kernel(
    const short* __restrict__ vh, short* __restrict__ vtf)
{
    __shared__ short T[64][72];
    const int tid = threadIdx.x;
    const int s  = blockIdx.y;          // head 0..31
    const int t0 = blockIdx.x * 64;     // l-tile (4 kb blocks)
    const size_t slab = (size_t)s * SLAB;

    {   // read 64 l-rows x 64 d (coalesced 32 B / thread)
        const int r = tid >> 2, c0 = (tid & 3) << 4;
        const short* src = vh + slab + (size_t)(t0 + r) * DHD + c0;
        short8 a = *(const short8*)src;
        short8 b = *(const short8*)(src + 8);
        *(short8*)&T[r][c0]     = a;
        *(short8*)&T[r][c0 + 8] = b;
    }
    __syncthreads();
    {   // write vtf[(kb*64 + d)*16 + ks] = T[kbl*16 + ks][d]  (32 B / thread)
        const int kbl = tid >> 6, d = tid & 63;
        short8 o0, o1;
        #pragma unroll
        for (int j = 0; j < 8; ++j) { o0[j] = T[kbl*16 + j][d]; o1[j] = T[kbl*16 + 8 + j][d]; }
        short* dst = vtf + slab + ((size_t)((t0 >> 4) + kbl) * 64 + d) * 16;
        *(short8*)dst       = o0;
        *(short8*)(dst + 8) = o1;
    }
}

// ---------------------------------------------------------------------------
// Attention, one WG (512 thr / 8 waves) per (bh, PAIR of 16-row q-tiles A,B).
// SWAPPED QK^T: mfma(K, Q) -> lane holds P[k=..+kg*4+{0..3}][q=fr].
//   Phase 1 (PAIRED): barrier-free per-wave K staging (counted vmcnt, loop is
//     vmem-exclusive: loads only). Each staged K tile feeds QK^T of BOTH
//     q-tiles (4 MFMAs/iter) -> K-staging traffic and WG count halve.
//   Softmax A -> paA f16 quads (sA dies), softmax B -> paB (sB dies).
//   Phase 2A then 2B: round-12's proven PV + NT-store loop (no counted vmcnt
//     here, so V loads/stores can't pollute a pipeline).
//   Epilogues via KBuf-aliased LDS reduce.
// ---------------------------------------------------------------------------
__global__ __launch_bounds__(512, 2) void attn_kernel(
    const _Float16* __restrict__ qf, const _Float16* __restrict__ kf,
    const _Float16* __restrict__ vtf,
    float* __restrict__ attn, float* __restrict__ ctx)
{
    __shared__ __align__(16) char KBuf[65536];        // 4 x 16 KB K tile slots
    __shared__ __align__(16) _Float16 PB[2][16][136]; // 8,704 B P tile (store path)
    __shared__ float redA[8][16];
    __shared__ float mrow[16], lirow[16];

    const int tid  = threadIdx.x;
    const int lane = tid & 63, wv = tid >> 6;
    const int fr = lane & 15, kg = lane >> 4;

    // head-major remap: all 64 q-pairs of head bh land on XCD (bh&7)
    const int wg  = blockIdx.x;                    // 0..2047
    const int rem = wg & 511;
    const int q0  = (rem >> 3) << 5;               // pair base (32 rows)
    const int bh  = ((wg >> 9) << 3) + (rem & 7);  // 0..31
    const size_t slab = (size_t)bh * SLAB;

    // Q fragments for both tiles (B-operand: lane fr holds its q-row)
    half8 qaA[2], qaB[2];
    #pragma unroll
    for (int ks = 0; ks < 2; ++ks) {
        qaA[ks] = *(const half8*)(qf + slab + (size_t)(q0 + fr) * DHD + ks*32 + kg*8);
        qaB[ks] = *(const half8*)(qf + slab + (size_t)(q0 + 16 + fr) * DHD + ks*32 + kg*8);
    }

    const int srow = lane >> 3;          // staging: row within 8-row block
    const int scb  = (lane & 7) ^ srow;  // pre-swizzled global 16B col-block
    const int klo = (wv << 4) + fr;      // tile-local K row (wave-private range)
    const int sw  = fr & 7;              // klo & 7
    const float C = 8.0f * 1.44269504089f;   // SCALE=8 folded into log2e

    #define STAGE_K(TI, CUR) { \
        _Pragma("unroll") \
        for (int j = 0; j < 2; ++j) { \
            const int b = wv*2 + j; \
            GLOAD_LDS16(kf + slab + (size_t)((TI)*128 + b*8 + srow)*DHD + scb*8, \
                        KBuf + (CUR)*16384 + b*1024); \
        } }

    // ========= Phase 1 (paired): one K staging feeds BOTH q-tiles =========
    f32x4 sA[16], sB[16];
    STAGE_K(0, 0); STAGE_K(1, 1); STAGE_K(2, 2);
    #pragma unroll
    for (int i = 0; i < 16; ++i) {
        if (i + 3 < 16) STAGE_K(i + 3, (i + 3) & 3);
        if      (i <= 12) VMCNT6();
        else if (i == 13) VMCNT4();
        else if (i == 14) VMCNT2();
        else              VMCNT0();

        const char* rp = KBuf + (i & 3)*16384 + (klo << 7);
        half8 kb0 = *(const half8*)(rp + ((kg ^ sw) << 4));
        half8 kb1 = *(const half8*)(rp + (((4 + kg) ^ sw) << 4));

        f32x4 a = {0.f,0.f,0.f,0.f};
        a = __builtin_amdgcn_mfma_f32_16x16x32_f16(kb0, qaA[0], a, 0,0,0);
        a = __builtin_amdgcn_mfma_f32_16x16x32_f16(kb1, qaA[1], a, 0,0,0);
        sA[i] = a;
        f32x4 b = {0.f,0.f,0.f,0.f};
        b = __builtin_amdgcn_mfma_f32_16x16x32_f16(kb0, qaB[0], b, 0,0,0);
        b = __builtin_amdgcn_mfma_f32_16x16x32_f16(kb1, qaB[1], b, 0,0,0);
        sB[i] = b;
    }
    #undef STAGE_K

    // ================= softmax A -> paA (sA dies) =========================
    h4_t paA[16];
    {
        f32x4 mx = sA[0];
        #pragma unroll
        for (int i = 1; i < 16; ++i) {
            mx.x = fmaxf(mx.x, sA[i].x); mx.y = fmaxf(mx.y, sA[i].y);
            mx.z = fmaxf(mx.z, sA[i].z); mx.w = fmaxf(mx.w, sA[i].w);
        }
        float m = fmaxf(fmaxf(mx.x, mx.y), fmaxf(mx.z, mx.w));
        m = fmaxf(m, __shfl_xor(m, 16));
        m = fmaxf(m, __shfl_xor(m, 32));
        if (lane < 16) redA[wv][lane] = m;
        __syncthreads();
        if (tid < 16) {
            float mm = redA[0][tid];
            #pragma unroll
            for (int w = 1; w < 8; ++w) mm = fmaxf(mm, redA[w][tid]);
            mrow[tid] = mm;
        }
        __syncthreads();
        m = mrow[fr];

        float sum = 0.f;
        #pragma unroll
        for (int i = 0; i < 16; ++i) {
            f32x4 p;
            p.x = exp2f((sA[i].x - m) * C);
            p.y = exp2f((sA[i].y - m) * C);
            p.z = exp2f((sA[i].z - m) * C);
            p.w = exp2f((sA[i].w - m) * C);
            sA[i] = p;
            sum += (p.x + p.y) + (p.z + p.w);
        }
        sum += __shfl_xor(sum, 16);
        sum += __shfl_xor(sum, 32);
        if (lane < 16) redA[wv][lane] = sum;
        __syncthreads();
        if (tid < 16) {
            float l = 0.f;
            #pragma unroll
            for (int w = 0; w < 8; ++w) l += redA[w][tid];
            lirow[tid] = 1.0f / l;
        }
        __syncthreads();
        const float li = lirow[fr];
        #pragma unroll
        for (int i = 0; i < 16; ++i) {
            paA[i][0] = (_Float16)(sA[i].x * li);
            paA[i][1] = (_Float16)(sA[i].y * li);
            paA[i][2] = (_Float16)(sA[i].z * li);
            paA[i][3] = (_Float16)(sA[i].w * li);
        }
    }
    __syncthreads();

    // ================= softmax B -> paB (sB dies) =========================
    h4_t paB[16];
    {
        f32x4 mx = sB[0];
        #pragma unroll
        for (int i = 1; i < 16; ++i) {
            mx.x = fmaxf(mx.x, sB[i].x); mx.y = fmaxf(mx.y, sB[i].y);
            mx.z = fmaxf(mx.z, sB[i].z); mx.w = fmaxf(mx.w, sB[i].w);
        }
        float m = fmaxf(fmaxf(mx.x, mx.y), fmaxf(mx.z, mx.w));
        m = fmaxf(m, __shfl_xor(m, 16));
        m = fmaxf(m, __shfl_xor(m, 32));
        if (lane < 16) redA[wv][lane] = m;
        __syncthreads();
        if (tid < 16) {
            float mm = redA[0][tid];
            #pragma unroll
            for (int w = 1; w < 8; ++w) mm = fmaxf(mm, redA[w][tid]);
            mrow[tid] = mm;
        }
        __syncthreads();
        m = mrow[fr];

        float sum = 0.f;
        #pragma unroll
        for (int i = 0; i < 16; ++i) {
            f32x4 p;
            p.x = exp2f((sB[i].x - m) * C);
            p.y = exp2f((sB[i].y - m) * C);
            p.z = exp2f((sB[i].z - m) * C);
            p.w = exp2f((sB[i].w - m) * C);
            sB[i] = p;
            sum += (p.x + p.y) + (p.z + p.w);
        }
        sum += __shfl_xor(sum, 16);
        sum += __shfl_xor(sum, 32);
        if (lane < 16) redA[wv][lane] = sum;
        __syncthreads();
        if (tid < 16) {
            float l = 0.f;
            #pragma unroll
            for (int w = 0; w < 8; ++w) l += redA[w][tid];
            lirow[tid] = 1.0f / l;
        }
        __syncthreads();
        const float li = lirow[fr];
        #pragma unroll
        for (int i = 0; i < 16; ++i) {
            paB[i][0] = (_Float16)(sB[i].x * li);
            paB[i][1] = (_Float16)(sB[i].y * li);
            paB[i][2] = (_Float16)(sB[i].z * li);
            paB[i][3] = (_Float16)(sB[i].w * li);
        }
    }

    // common phase-2 state
    const _Float16* vfb = vtf + slab;        // fragment-major V
    const int sq = tid >> 5, sc = tid & 31;  // store mapping: row q, 4-col chunk
    float* abaseA = attn + ((size_t)bh * LSEQ + q0 + sq) * LSEQ + (sc << 2);
    float* abaseB = abaseA + (size_t)16 * LSEQ;
    f32x4 acc[4];
    int cur = 0;

    // ================= phase 2A: PV + NT-store tile A ======================
    #pragma unroll
    for (int db = 0; db < 4; ++db) { f32x4 z = {0.f,0.f,0.f,0.f}; acc[db] = z; }
    #pragma unroll
    for (int t = 0; t < 16; ++t) {
        h4_t pw = paA[t];
        *(h4_t*)&PB[cur][fr][(wv << 4) + (kg << 2)] = pw;
        const _Float16* vb = vfb + ((size_t)(t*8 + wv) << 10) + (fr << 4) + (kg << 2);
        #pragma unroll
        for (int db = 0; db < 4; ++db) {
            h4_t va = *(const h4_t*)(vb + db*256);
            acc[db] = __builtin_amdgcn_mfma_f32_16x16x16f16(va, pw, acc[db], 0,0,0);
        }
        LGKM0();
        BARRIER();
        h4_t pr = *(const h4_t*)&PB[cur][sq][sc << 2];
        f4raw o = { (float)pr[0], (float)pr[1], (float)pr[2], (float)pr[3] };
        __builtin_nontemporal_store(o, (f4raw*)(abaseA + (size_t)t * 128));
        cur ^= 1;
    }

    // ================= epilogue A: ctx rows q0..q0+15 ======================
    __syncthreads();
    {
        float* pt = (float*)KBuf;            // [8][16][64]
        #pragma unroll
        for (int db = 0; db < 4; ++db) {
            float4 o = { acc[db].x, acc[db].y, acc[db].z, acc[db].w };
            *(float4*)(pt + wv*1024 + fr*64 + db*16 + (kg << 2)) = o;
        }
    }
    __syncthreads();
    {
        float* pt = (float*)KBuf;
        const int e = tid << 1;              // 512 thr x 2 floats = 16x64
        const int q = e >> 6, d = e & 63;
        float2 r2 = {0.f, 0.f};
        #pragma unroll
        for (int w = 0; w < 8; ++w) {
            float2 t2 = *(float2*)(pt + w*1024 + q*64 + d);
            r2.x += t2.x; r2.y += t2.y;
        }
        *(float2*)(ctx + slab + (size_t)(q0 + q) * DHD + d) = r2;
    }
    __syncthreads();

    // ================= phase 2B: PV + NT-store tile B ======================
    #pragma unroll
    for (int db = 0; db < 4; ++db) { f32x4 z = {0.f,0.f,0.f,0.f}; acc[db] = z; }
    #pragma unroll
    for (int t = 0; t < 16; ++t) {
        h4_t pw = paB[t];
        *(h4_t*)&PB[cur][fr][(wv << 4) + (kg << 2)] = pw;
        const _Float16* vb = vfb + ((size_t)(t*8 + wv) << 10) + (fr << 4) + (kg << 2);
        #pragma unroll
        for (int db = 0; db < 4; ++db) {
            h4_t va = *(const h4_t*)(vb + db*256);
            acc[db] = __builtin_amdgcn_mfma_f32_16x16x16f16(va, pw, acc[db], 0,0,0);
        }
        LGKM0();
        BARRIER();
        h4_t pr = *(const h4_t*)&PB[cur][sq][sc << 2];
        f4raw o = { (float)pr[0], (float)pr[1], (float)pr[2], (float)pr[3] };
        __builtin_nontemporal_store(o, (f4raw*)(abaseB + (size_t)t * 128));
        cur ^= 1;
    }

    // ================= epilogue B: ctx rows q0+16..q0+31 ===================
    __syncthreads();
    {
        float* pt = (float*)KBuf;
        #pragma unroll
        for (int db = 0; db < 4; ++db) {
            float4 o = { acc[db].x, acc[db].y, acc[db].z, acc[db].w };
            *(float4*)(pt + wv*1024 + fr*64 + db*16 + (kg << 2)) = o;
        }
    }
    __syncthreads();
    {
        float* pt = (float*)KBuf;
        const int e = tid << 1;
        const int q = e >> 6, d = e & 63;
        float2 r2 = {0.f, 0.f};
        #pragma unroll
        for (int w = 0; w < 8; ++w) {
            float2 t2 = *(float2*)(pt + w*1024 + q*64 + d);
            r2.x += t2.x; r2.y += t2.y;
        }
        *(float2*)(ctx + slab + (size_t)(q0 + 16 + q) * DHD + d) = r2;
    }
}

// ---------------------------------------------------------------------------
// Residual + LayerNorm: out = LN(resid + x) * gamma + beta, one row per block
// ---------------------------------------------------------------------------
__global__ __launch_bounds__(128) void ln_kernel(
    const float* __restrict__ resid, const float* __restrict__ x,
    const float* __restrict__ gamma, const float* __restrict__ beta,
    float* __restrict__ out)
{
    const int row = blockIdx.x;
    const int tid = threadIdx.x;
    const size_t base = (size_t)row * DMODEL + tid*4;

    float4 v = *(const float4*)(x + base);
    float4 rq = *(const float4*)(resid + base);
    v.x += rq.x; v.y += rq.y; v.z += rq.z; v.w += rq.w;

    float s  = v.x + v.y + v.z + v.w;
    float ss = v.x*v.x + v.y*v.y + v.z*v.z + v.w*v.w;
    #pragma unroll
    for (int d = 1; d < 64; d <<= 1) { s += __shfl_xor(s, d); ss += __shfl_xor(ss, d); }

    __shared__ float red[2][2];
    const int wv = tid >> 6;
    if ((tid & 63) == 0) { red[wv][0] = s; red[wv][1] = ss; }
    __syncthreads();
    s  = red[0][0] + red[1][0];
    ss = red[0][1] + red[1][1];

    const float mu  = s * (1.0f/512.0f);
    const float var = ss * (1.0f/512.0f) - mu*mu;
    const float rs  = rsqrtf(var + 1e-5f);

    float4 g = *(const float4*)(gamma + tid*4);
    float4 b = *(const float4*)(beta + tid*4);
    float4 o;
    o.x = (v.x - mu) * rs * g.x + b.x;
    o.y = (v.y - mu) * rs * g.y + b.y;
    o.z = (v.z - mu) * rs * g.z + b.z;
    o.w = (v.w - mu) * rs * g.w + b.w;
    *(float4*)(out + base) = o;
}

// ---------------------------------------------------------------------------
extern "C" void kernel_launch(void* const* d_in, const int* in_sizes, int n_in,
                              void* d_out, int out_size, void* d_ws, size_t ws_size,
                              hipStream_t stream)
{
    const float* query = (const float*)d_in[0];
    const float* key   = (const float*)d_in[1];
    const float* value = (const float*)d_in[2];
    const float* Wq = (const float*)d_in[3];
    const float* bq = (const float*)d_in[4];
    const float* Wk = (const float*)d_in[5];
    const float* bk = (const float*)d_in[6];
    const float* Wv = (const float*)d_in[7];
    const float* bv = (const float*)d_in[8];
    const float* Wo = (const float*)d_in[9];
    const float* bo = (const float*)d_in[10];
    const float* gamma = (const float*)d_in[11];
    const float* beta  = (const float*)d_in[12];

    float* out  = (float*)d_out;            // [B,L,D] = 4,194,304 f32
    float* attn = out + 4194304;            // [32,2048,2048] f32

    const size_t NTOK = (size_t)8192 * 512; // 4,194,304 elements
    short* qv = (short*)d_ws;               // f16 projected tensors
    short* kv = qv + NTOK;
    short* vf = kv + NTOK;
    short* vtf = vf + NTOK;                 // fragment-major V^T per head
    // obuf aliases qv/kv (dead after attn_kernel); ws requirement = 32 MB
    float* obuf = (float*)d_ws;

    dim3 pgrid(8, 128), pblk(256);
    proj_gemm<3><<<pgrid, pblk, 0, stream>>>(query, Wq, bq, nullptr, qv);
    proj_gemm<3><<<pgrid, pblk, 0, stream>>>(key,   Wk, bk, nullptr, kv);
    proj_gemm<3><<<pgrid, pblk, 0, stream>>>(value, Wv, bv, nullptr, vf);

    vtransf_kernel<<<dim3(32, 32), 256, 0, stream>>>(vf, vtf);

    attn_kernel<<<2048, 512, 0, stream>>>((const _Float16*)qv, (const _Float16*)kv,
                                          (const _Float16*)vtf, attn, out /*ctx*/);

    proj_gemm<0><<<pgrid, pblk, 0, stream>>>(out /*ctx*/, Wo, bo, obuf, nullptr);
    ln_kernel<<<8192, 128, 0, stream>>>(query, obuf, gamma, beta, out);
}

// Round 15
// 286.312 us; speedup vs baseline: 1.1864x; 1.1544x over previous
//
#include <hip/hip_runtime.h>

// Problem constants
#define LSEQ 2048
#define DMODEL 512
#define DHD 64          // head dim of the (faithful) raw view
#define SLAB (LSEQ*DHD) // 131072 elements per contiguous head slab

typedef __attribute__((ext_vector_type(8))) short short8;
typedef __attribute__((ext_vector_type(4))) float f32x4;
typedef float f4raw __attribute__((ext_vector_type(4)));   // raw clang vector (NT-store legal)
typedef _Float16 half8 __attribute__((ext_vector_type(8)));
typedef _Float16 h4_t  __attribute__((ext_vector_type(4)));

__device__ __forceinline__ short f2bf(float x) {   // round-to-nearest-even bf16
    union { float f; unsigned u; } v; v.f = x;
    unsigned r = v.u + 0x7FFF + ((v.u >> 16) & 1);
    return (short)(r >> 16);
}
__device__ __forceinline__ float bf2f(short h) {
    union { float f; unsigned u; } v; v.u = ((unsigned)(unsigned short)h) << 16;
    return v.f;
}

// direct global->LDS async copy, 16 B per lane (dest = wave-uniform base + lane*16)
#define GLOAD_LDS16(g, l) __builtin_amdgcn_global_load_lds( \
    (const __attribute__((address_space(1))) void*)(g),     \
    (__attribute__((address_space(3))) void*)(l), 16, 0, 0)

#define VMCNT0()  asm volatile("s_waitcnt vmcnt(0)" ::: "memory")
#define VMCNT2()  asm volatile("s_waitcnt vmcnt(2)" ::: "memory")
#define VMCNT4()  asm volatile("s_waitcnt vmcnt(4)" ::: "memory")
#define VMCNT6()  asm volatile("s_waitcnt vmcnt(6)" ::: "memory")
#define LGKM0()   asm volatile("s_waitcnt lgkmcnt(0)" ::: "memory")
#define BARRIER() do { __builtin_amdgcn_s_barrier(); __builtin_amdgcn_sched_barrier(0); } while (0)

// ---------------------------------------------------------------------------
// Projection GEMM: C[8192,512] = A[8192,512] @ W[512,512]^T + bias
// Internally split-f32 precision: a*w ~= ah*wh + ah*wl + al*wh (3 bf16 MFMAs).
// MODE 0: write f32 Cf.   MODE 3: write f16 C0 (round once at the end).
// ---------------------------------------------------------------------------
template<int MODE>
__global__ __launch_bounds__(256) void proj_gemm(
    const float* __restrict__ A, const float* __restrict__ W,
    const float* __restrict__ bias, float* __restrict__ Cf,
    short* __restrict__ C0)
{
    __shared__ __align__(16) short Ah[64][40], Al[64][40], Bh[64][40], Bl[64][40];

    const int tid  = threadIdx.x;
    const int lane = tid & 63, wv = tid >> 6;
    const int wm = wv >> 1, wn = wv & 1;
    const int fr = lane & 15, kg = lane >> 4;
    const int m0 = blockIdx.y * 64, n0 = blockIdx.x * 64;

    f32x4 acc[2][2];
    #pragma unroll
    for (int i = 0; i < 2; ++i)
        #pragma unroll
        for (int j = 0; j < 2; ++j) { f32x4 z = {0.f,0.f,0.f,0.f}; acc[i][j] = z; }

    const int srow = tid >> 2, sc8 = (tid & 3) << 3;

    for (int kt = 0; kt < 16; ++kt) {
        __syncthreads();
        {   // stage A/W tile, converting f32 -> hi/lo bf16
            const float* ap = A + (size_t)(m0 + srow) * DMODEL + kt*32 + sc8;
            float4 a0 = *(const float4*)ap;
            float4 a1 = *(const float4*)(ap + 4);
            float va[8] = {a0.x,a0.y,a0.z,a0.w,a1.x,a1.y,a1.z,a1.w};
            short8 h, l;
            #pragma unroll
            for (int j = 0; j < 8; ++j) { short hh = f2bf(va[j]); h[j] = hh; l[j] = f2bf(va[j] - bf2f(hh)); }
            *(short8*)&Ah[srow][sc8] = h; *(short8*)&Al[srow][sc8] = l;

            const float* wp = W + (size_t)(n0 + srow) * DMODEL + kt*32 + sc8;
            float4 b0 = *(const float4*)wp;
            float4 b1 = *(const float4*)(wp + 4);
            float vb[8] = {b0.x,b0.y,b0.z,b0.w,b1.x,b1.y,b1.z,b1.w};
            #pragma unroll
            for (int j = 0; j < 8; ++j) { short hh = f2bf(vb[j]); h[j] = hh; l[j] = f2bf(vb[j] - bf2f(hh)); }
            *(short8*)&Bh[srow][sc8] = h; *(short8*)&Bl[srow][sc8] = l;
        }
        __syncthreads();

        short8 ah[2], al[2], bh[2], bl[2];
        #pragma unroll
        for (int mf = 0; mf < 2; ++mf) {
            ah[mf] = *(short8*)&Ah[wm*32 + mf*16 + fr][kg*8];
            al[mf] = *(short8*)&Al[wm*32 + mf*16 + fr][kg*8];
        }
        #pragma unroll
        for (int nf = 0; nf < 2; ++nf) {
            bh[nf] = *(short8*)&Bh[wn*32 + nf*16 + fr][kg*8];
            bl[nf] = *(short8*)&Bl[wn*32 + nf*16 + fr][kg*8];
        }
        #pragma unroll
        for (int mf = 0; mf < 2; ++mf)
            #pragma unroll
            for (int nf = 0; nf < 2; ++nf) {
                acc[mf][nf] = __builtin_amdgcn_mfma_f32_16x16x32_bf16(ah[mf], bh[nf], acc[mf][nf], 0,0,0);
                acc[mf][nf] = __builtin_amdgcn_mfma_f32_16x16x32_bf16(ah[mf], bl[nf], acc[mf][nf], 0,0,0);
                acc[mf][nf] = __builtin_amdgcn_mfma_f32_16x16x32_bf16(al[mf], bh[nf], acc[mf][nf], 0,0,0);
            }
    }

    // epilogue: C/D layout col=lane&15, row=(lane>>4)*4+reg
    #pragma unroll
    for (int mf = 0; mf < 2; ++mf)
        #pragma unroll
        for (int nf = 0; nf < 2; ++nf) {
            const int col = n0 + wn*32 + nf*16 + fr;
            const float bv = bias[col];
            #pragma unroll
            for (int r = 0; r < 4; ++r) {
                const int row = m0 + wm*32 + mf*16 + kg*4 + r;
                const float o = acc[mf][nf][r] + bv;
                const size_t idx = (size_t)row * DMODEL + col;
                if (MODE == 0) Cf[idx] = o;
                else           ((_Float16*)C0)[idx] = (_Float16)o;
            }
        }
}

// ---------------------------------------------------------------------------
// V transpose -> FRAGMENT-MAJOR layout: vtf[head][kb][d][ks] with k = kb*16+ks.
// ---------------------------------------------------------------------------
__global__ __launch_bounds__(256) void vtransf_kernel(
    const short* __restrict__ vh, short* __restrict__ vtf)
{
    __shared__ short T[64][72];
    const int tid = threadIdx.x;
    const int s  = blockIdx.y;          // head 0..31
    const int t0 = blockIdx.x * 64;     // l-tile (4 kb blocks)
    const size_t slab = (size_t)s * SLAB;

    {   // read 64 l-rows x 64 d (coalesced 32 B / thread)
        const int r = tid >> 2, c0 = (tid & 3) << 4;
        const short* src = vh + slab + (size_t)(t0 + r) * DHD + c0;
        short8 a = *(const short8*)src;
        short8 b = *(const short8*)(src + 8);
        *(short8*)&T[r][c0]     = a;
        *(short8*)&T[r][c0 + 8] = b;
    }
    __syncthreads();
    {   // write vtf[(kb*64 + d)*16 + ks] = T[kbl*16 + ks][d]  (32 B / thread)
        const int kbl = tid >> 6, d = tid & 63;
        short8 o0, o1;
        #pragma unroll
        for (int j = 0; j < 8; ++j) { o0[j] = T[kbl*16 + j][d]; o1[j] = T[kbl*16 + 8 + j][d]; }
        short* dst = vtf + slab + ((size_t)((t0 >> 4) + kbl) * 64 + d) * 16;
        *(short8*)dst       = o0;
        *(short8*)(dst + 8) = o1;
    }
}

// ---------------------------------------------------------------------------
// Attention, one WG (512 thr / 8 waves) per (bh, 16-row q-tile). Single pass.
// SWAPPED QK^T: mfma(K, Q) -> lane holds P[k=i*128+wv*16+kg*4+{0..3}][q=fr].
//   Phase 1: round-12 proven barrier-free per-wave K staging (counted vmcnt,
//            vmem-exclusive loop), 4-slot rotation in UBuf.
//   Softmax: scalar per-lane m/li -> normalized quads kept in s[].
//   Phase 2 (NEW): compute loop with ZERO barriers — P quads written to a
//     full 16-tile PBall (aliases dead K slots), V loads + PV MFMAs free-run;
//     then ONE LGKM0+BARRIER; then a dense NT-store sweep (16 dwordx4/thread).
//   Epilogue: 8-way k-slice reduce via UBuf-aliased LDS.
// ---------------------------------------------------------------------------
__global__ __launch_bounds__(512, 4) void attn_kernel(
    const _Float16* __restrict__ qf, const _Float16* __restrict__ kf,
    const _Float16* __restrict__ vtf,
    float* __restrict__ attn, float* __restrict__ ctx)
{
    // union buffer: phase-1 K slots (4x16KB=64KB) / PBall [16][2068] f16
    // (66,176B) / epilogue partials [8][16][64] f32 (32KB)
    __shared__ __align__(16) char UBuf[66176];
    __shared__ float redA[8][16];
    __shared__ float mrow[16], lirow[16];

    const int tid  = threadIdx.x;
    const int lane = tid & 63, wv = tid >> 6;
    const int fr = lane & 15, kg = lane >> 4;

    // head-major remap: all 128 q-tiles of head bh land on XCD (bh&7)
    const int wg  = blockIdx.x;
    const int rem = wg & 1023;
    const int q0  = (rem >> 3) << 4;               // q-tile * 16
    const int bh  = ((wg >> 10) << 3) + (rem & 7); // 0..31
    const size_t slab = (size_t)bh * SLAB;

    // Q fragments (B-operand: lane fr holds row q0+fr), replicated across waves
    half8 qa[2];
    #pragma unroll
    for (int ks = 0; ks < 2; ++ks)
        qa[ks] = *(const half8*)(qf + slab + (size_t)(q0 + fr) * DHD + ks*32 + kg*8);

    const int srow = lane >> 3;          // staging: row within 8-row block
    const int scb  = (lane & 7) ^ srow;  // pre-swizzled global 16B col-block

    f32x4 s[16];   // logit quads: k = i*128 + wv*16 + kg*4 + r,  q = q0 + fr

    // ---- Phase 1: QK^T (swapped), barrier-free per-wave 4-slot pipeline ----
    #define STAGE_K(TI, CUR) { \
        _Pragma("unroll") \
        for (int j = 0; j < 2; ++j) { \
            const int b = wv*2 + j; \
            GLOAD_LDS16(kf + slab + (size_t)((TI)*128 + b*8 + srow)*DHD + scb*8, \
                        UBuf + (CUR)*16384 + b*1024); \
        } }

    STAGE_K(0, 0);
    STAGE_K(1, 1);
    STAGE_K(2, 2);

    const int klo = (wv << 4) + fr;          // tile-local K row (wave-private range)
    const int sw  = fr & 7;                  // klo & 7
    #pragma unroll
    for (int i = 0; i < 16; ++i) {
        if (i + 3 < 16) STAGE_K(i + 3, (i + 3) & 3);

        // wait for tile i only: allowed outstanding = 2*min(3, 15-i)
        if      (i <= 12) VMCNT6();
        else if (i == 13) VMCNT4();
        else if (i == 14) VMCNT2();
        else              VMCNT0();

        const char* rp = UBuf + (i & 3)*16384 + (klo << 7);
        half8 kb0 = *(const half8*)(rp + ((kg ^ sw) << 4));
        half8 kb1 = *(const half8*)(rp + (((4 + kg) ^ sw) << 4));

        f32x4 a = {0.f,0.f,0.f,0.f};
        a = __builtin_amdgcn_mfma_f32_16x16x32_f16(kb0, qa[0], a, 0,0,0);  // SWAPPED
        a = __builtin_amdgcn_mfma_f32_16x16x32_f16(kb1, qa[1], a, 0,0,0);
        s[i] = a;
    }
    #undef STAGE_K

    // ---- softmax: all 4 quad comps share q = fr -> scalar m / li ----
    float m;
    {
        f32x4 mx = s[0];
        #pragma unroll
        for (int i = 1; i < 16; ++i) {
            mx.x = fmaxf(mx.x, s[i].x); mx.y = fmaxf(mx.y, s[i].y);
            mx.z = fmaxf(mx.z, s[i].z); mx.w = fmaxf(mx.w, s[i].w);
        }
        m = fmaxf(fmaxf(mx.x, mx.y), fmaxf(mx.z, mx.w));
        m = fmaxf(m, __shfl_xor(m, 16));
        m = fmaxf(m, __shfl_xor(m, 32));
    }
    if (lane < 16) redA[wv][lane] = m;
    __syncthreads();
    if (tid < 16) {
        float mm = redA[0][tid];
        #pragma unroll
        for (int w = 1; w < 8; ++w) mm = fmaxf(mm, redA[w][tid]);
        mrow[tid] = mm;
    }
    __syncthreads();
    m = mrow[fr];

    const float C = 8.0f * 1.44269504089f;   // SCALE=8 folded into log2e
    float sum = 0.f;
    #pragma unroll
    for (int i = 0; i < 16; ++i) {
        f32x4 p;
        p.x = exp2f((s[i].x - m) * C);
        p.y = exp2f((s[i].y - m) * C);
        p.z = exp2f((s[i].z - m) * C);
        p.w = exp2f((s[i].w - m) * C);
        s[i] = p;
        sum += (p.x + p.y) + (p.z + p.w);
    }
    sum += __shfl_xor(sum, 16);
    sum += __shfl_xor(sum, 32);
    if (lane < 16) redA[wv][lane] = sum;
    __syncthreads();
    if (tid < 16) {
        float l = 0.f;
        #pragma unroll
        for (int w = 0; w < 8; ++w) l += redA[w][tid];
        lirow[tid] = 1.0f / l;
    }
    __syncthreads();   // also: all waves done with UBuf K slots -> PBall safe
    const float li = lirow[fr];

    // ---- Phase 2: barrier-free compute loop (PBall writes + V loads + PV) ----
    f32x4 acc[4];
    #pragma unroll
    for (int db = 0; db < 4; ++db) { f32x4 z = {0.f,0.f,0.f,0.f}; acc[db] = z; }

    _Float16* PBall = (_Float16*)UBuf;       // [16][2068]
    const _Float16* vfb = vtf + slab;        // fragment-major V
    const int pcol = (wv << 4) + (kg << 2);

    #pragma unroll
    for (int t = 0; t < 16; ++t) {
        // normalized P quad (k = t*128 + wv*16 + kg*4 + r, q = fr)
        f32x4 p = s[t];
        p.x *= li; p.y *= li; p.z *= li; p.w *= li;
        h4_t pw = { (_Float16)p.x, (_Float16)p.y, (_Float16)p.z, (_Float16)p.w };

        // P write into the full-tile buffer (8 B contiguous per lane)
        *(h4_t*)&PBall[(size_t)fr * 2068 + t*128 + pcol] = pw;

        // PV: A-frag = 512 B contiguous wave load from vtf block kb = t*8+wv
        const _Float16* vb = vfb + ((size_t)(t*8 + wv) << 10) + (fr << 4) + (kg << 2);
        #pragma unroll
        for (int db = 0; db < 4; ++db) {
            h4_t va = *(const h4_t*)(vb + db*256);
            acc[db] = __builtin_amdgcn_mfma_f32_16x16x16f16(va, pw, acc[db], 0,0,0);
        }
    }

    LGKM0();                   // all 16 PBall writes of this wave visible
    BARRIER();                 // whole 16x2048 P tile ready

    // ---- dense NT-store sweep: 16 back-to-back dwordx4 per thread ----
    {
        const int sq = tid >> 5, sc = tid & 31;
        float* abase = attn + ((size_t)bh * LSEQ + q0 + sq) * LSEQ + (sc << 2);
        const _Float16* prow = &PBall[(size_t)sq * 2068 + (sc << 2)];
        #pragma unroll
        for (int i = 0; i < 16; ++i) {
            h4_t pr = *(const h4_t*)(prow + i*128);
            f4raw o = { (float)pr[0], (float)pr[1], (float)pr[2], (float)pr[3] };
            __builtin_nontemporal_store(o, (f4raw*)(abase + (size_t)i * 128));
        }
    }

    // ---- epilogue: 8-way k-slice reduce (aliases UBuf) ----
    __syncthreads();
    {
        float* pt = (float*)UBuf;            // [8][16][64]
        #pragma unroll
        for (int db = 0; db < 4; ++db) {
            float4 o = { acc[db].x, acc[db].y, acc[db].z, acc[db].w };
            *(float4*)(pt + wv*1024 + fr*64 + db*16 + (kg << 2)) = o;
        }
    }
    __syncthreads();
    {
        float* pt = (float*)UBuf;
        const int e = tid << 1;              // 512 thr x 2 floats = 16x64
        const int q = e >> 6, d = e & 63;
        float2 r2 = {0.f, 0.f};
        #pragma unroll
        for (int w = 0; w < 8; ++w) {
            float2 t2 = *(float2*)(pt + w*1024 + q*64 + d);
            r2.x += t2.x; r2.y += t2.y;
        }
        *(float2*)(ctx + slab + (size_t)(q0 + q) * DHD + d) = r2;
    }
}

// ---------------------------------------------------------------------------
// Residual + LayerNorm: out = LN(resid + x) * gamma + beta, one row per block
// ---------------------------------------------------------------------------
__global__ __launch_bounds__(128) void ln_kernel(
    const float* __restrict__ resid, const float* __restrict__ x,
    const float* __restrict__ gamma, const float* __restrict__ beta,
    float* __restrict__ out)
{
    const int row = blockIdx.x;
    const int tid = threadIdx.x;
    const size_t base = (size_t)row * DMODEL + tid*4;

    float4 v = *(const float4*)(x + base);
    float4 rq = *(const float4*)(resid + base);
    v.x += rq.x; v.y += rq.y; v.z += rq.z; v.w += rq.w;

    float s  = v.x + v.y + v.z + v.w;
    float ss = v.x*v.x + v.y*v.y + v.z*v.z + v.w*v.w;
    #pragma unroll
    for (int d = 1; d < 64; d <<= 1) { s += __shfl_xor(s, d); ss += __shfl_xor(ss, d); }

    __shared__ float red[2][2];
    const int wv = tid >> 6;
    if ((tid & 63) == 0) { red[wv][0] = s; red[wv][1] = ss; }
    __syncthreads();
    s  = red[0][0] + red[1][0];
    ss = red[0][1] + red[1][1];

    const float mu  = s * (1.0f/512.0f);
    const float var = ss * (1.0f/512.0f) - mu*mu;
    const float rs  = rsqrtf(var + 1e-5f);

    float4 g = *(const float4*)(gamma + tid*4);
    float4 b = *(const float4*)(beta + tid*4);
    float4 o;
    o.x = (v.x - mu) * rs * g.x + b.x;
    o.y = (v.y - mu) * rs * g.y + b.y;
    o.z = (v.z - mu) * rs * g.z + b.z;
    o.w = (v.w - mu) * rs * g.w + b.w;
    *(float4*)(out + base) = o;
}

// ---------------------------------------------------------------------------
extern "C" void kernel_launch(void* const* d_in, const int* in_sizes, int n_in,
                              void* d_out, int out_size, void* d_ws, size_t ws_size,
                              hipStream_t stream)
{
    const float* query = (const float*)d_in[0];
    const float* key   = (const float*)d_in[1];
    const float* value = (const float*)d_in[2];
    const float* Wq = (const float*)d_in[3];
    const float* bq = (const float*)d_in[4];
    const float* Wk = (const float*)d_in[5];
    const float* bk = (const float*)d_in[6];
    const float* Wv = (const float*)d_in[7];
    const float* bv = (const float*)d_in[8];
    const float* Wo = (const float*)d_in[9];
    const float* bo = (const float*)d_in[10];
    const float* gamma = (const float*)d_in[11];
    const float* beta  = (const float*)d_in[12];

    float* out  = (float*)d_out;            // [B,L,D] = 4,194,304 f32
    float* attn = out + 4194304;            // [32,2048,2048] f32

    const size_t NTOK = (size_t)8192 * 512; // 4,194,304 elements
    short* qv = (short*)d_ws;               // f16 projected tensors
    short* kv = qv + NTOK;
    short* vf = kv + NTOK;
    short* vtf = vf + NTOK;                 // fragment-major V^T per head
    // obuf aliases qv/kv (dead after attn_kernel); ws requirement = 32 MB
    float* obuf = (float*)d_ws;

    dim3 pgrid(8, 128), pblk(256);
    proj_gemm<3><<<pgrid, pblk, 0, stream>>>(query, Wq, bq, nullptr, qv);
    proj_gemm<3><<<pgrid, pblk, 0, stream>>>(key,   Wk, bk, nullptr, kv);
    proj_gemm<3><<<pgrid, pblk, 0, stream>>>(value, Wv, bv, nullptr, vf);

    vtransf_kernel<<<dim3(32, 32), 256, 0, stream>>>(vf, vtf);

    attn_kernel<<<4096, 512, 0, stream>>>((const _Float16*)qv, (const _Float16*)kv,
                                          (const _Float16*)vtf, attn, out /*ctx*/);

    proj_gemm<0><<<pgrid, pblk, 0, stream>>>(out /*ctx*/, Wo, bo, obuf, nullptr);
    ln_kernel<<<8192, 128, 0, stream>>>(query, obuf, gamma, beta, out);
}

// Round 17
// 286.289 us; speedup vs baseline: 1.1864x; 1.0001x over previous
//
#include <hip/hip_runtime.h>

// Problem constants
#define LSEQ 2048
#define DMODEL 512
#define DHD 64          // head dim of the (faithful) raw view
#define SLAB (LSEQ*DHD) // 131072 elements per contiguous head slab

typedef __attribute__((ext_vector_type(8))) short short8;
typedef __attribute__((ext_vector_type(4))) float f32x4;
typedef float f4raw __attribute__((ext_vector_type(4)));   // raw clang vector (NT-store legal)
typedef _Float16 half8 __attribute__((ext_vector_type(8)));
typedef _Float16 h4_t  __attribute__((ext_vector_type(4)));

__device__ __forceinline__ short f2bf(float x) {   // round-to-nearest-even bf16
    union { float f; unsigned u; } v; v.f = x;
    unsigned r = v.u + 0x7FFF + ((v.u >> 16) & 1);
    return (short)(r >> 16);
}
__device__ __forceinline__ float bf2f(short h) {
    union { float f; unsigned u; } v; v.u = ((unsigned)(unsigned short)h) << 16;
    return v.f;
}

// direct global->LDS async copy, 16 B per lane (dest = wave-uniform base + lane*16)
#define GLOAD_LDS16(g, l) __builtin_amdgcn_global_load_lds( \
    (const __attribute__((address_space(1))) void*)(g),     \
    (__attribute__((address_space(3))) void*)(l), 16, 0, 0)

#define VMCNT0()  asm volatile("s_waitcnt vmcnt(0)" ::: "memory")
#define VMCNT2()  asm volatile("s_waitcnt vmcnt(2)" ::: "memory")
#define VMCNT4()  asm volatile("s_waitcnt vmcnt(4)" ::: "memory")
#define LGKM0()   asm volatile("s_waitcnt lgkmcnt(0)" ::: "memory")
#define SCHEDB()  __builtin_amdgcn_sched_barrier(0)
#define BARRIER() do { __builtin_amdgcn_s_barrier(); __builtin_amdgcn_sched_barrier(0); } while (0)

// ---------------------------------------------------------------------------
// Projection GEMM: C[8192,512] = A[8192,512] @ W[512,512]^T + bias
// Internally split-f32 precision: a*w ~= ah*wh + ah*wl + al*wh (3 bf16 MFMAs).
// MODE 0: write f32 Cf.   MODE 3: write f16 C0 (round once at the end).
// ---------------------------------------------------------------------------
template<int MODE>
__global__ __launch_bounds__(256) void proj_gemm(
    const float* __restrict__ A, const float* __restrict__ W,
    const float* __restrict__ bias, float* __restrict__ Cf,
    short* __restrict__ C0)
{
    __shared__ __align__(16) short Ah[64][40], Al[64][40], Bh[64][40], Bl[64][40];

    const int tid  = threadIdx.x;
    const int lane = tid & 63, wv = tid >> 6;
    const int wm = wv >> 1, wn = wv & 1;
    const int fr = lane & 15, kg = lane >> 4;
    const int m0 = blockIdx.y * 64, n0 = blockIdx.x * 64;

    f32x4 acc[2][2];
    #pragma unroll
    for (int i = 0; i < 2; ++i)
        #pragma unroll
        for (int j = 0; j < 2; ++j) { f32x4 z = {0.f,0.f,0.f,0.f}; acc[i][j] = z; }

    const int srow = tid >> 2, sc8 = (tid & 3) << 3;

    for (int kt = 0; kt < 16; ++kt) {
        __syncthreads();
        {   // stage A/W tile, converting f32 -> hi/lo bf16
            const float* ap = A + (size_t)(m0 + srow) * DMODEL + kt*32 + sc8;
            float4 a0 = *(const float4*)ap;
            float4 a1 = *(const float4*)(ap + 4);
            float va[8] = {a0.x,a0.y,a0.z,a0.w,a1.x,a1.y,a1.z,a1.w};
            short8 h, l;
            #pragma unroll
            for (int j = 0; j < 8; ++j) { short hh = f2bf(va[j]); h[j] = hh; l[j] = f2bf(va[j] - bf2f(hh)); }
            *(short8*)&Ah[srow][sc8] = h; *(short8*)&Al[srow][sc8] = l;

            const float* wp = W + (size_t)(n0 + srow) * DMODEL + kt*32 + sc8;
            float4 b0 = *(const float4*)wp;
            float4 b1 = *(const float4*)(wp + 4);
            float vb[8] = {b0.x,b0.y,b0.z,b0.w,b1.x,b1.y,b1.z,b1.w};
            #pragma unroll
            for (int j = 0; j < 8; ++j) { short hh = f2bf(vb[j]); h[j] = hh; l[j] = f2bf(vb[j] - bf2f(hh)); }
            *(short8*)&Bh[srow][sc8] = h; *(short8*)&Bl[srow][sc8] = l;
        }
        __syncthreads();

        short8 ah[2], al[2], bh[2], bl[2];
        #pragma unroll
        for (int mf = 0; mf < 2; ++mf) {
            ah[mf] = *(short8*)&Ah[wm*32 + mf*16 + fr][kg*8];
            al[mf] = *(short8*)&Al[wm*32 + mf*16 + fr][kg*8];
        }
        #pragma unroll
        for (int nf = 0; nf < 2; ++nf) {
            bh[nf] = *(short8*)&Bh[wn*32 + nf*16 + fr][kg*8];
            bl[nf] = *(short8*)&Bl[wn*32 + nf*16 + fr][kg*8];
        }
        #pragma unroll
        for (int mf = 0; mf < 2; ++mf)
            #pragma unroll
            for (int nf = 0; nf < 2; ++nf) {
                acc[mf][nf] = __builtin_amdgcn_mfma_f32_16x16x32_bf16(ah[mf], bh[nf], acc[mf][nf], 0,0,0);
                acc[mf][nf] = __builtin_amdgcn_mfma_f32_16x16x32_bf16(ah[mf], bl[nf], acc[mf][nf], 0,0,0);
                acc[mf][nf] = __builtin_amdgcn_mfma_f32_16x16x32_bf16(al[mf], bh[nf], acc[mf][nf], 0,0,0);
            }
    }

    // epilogue: C/D layout col=lane&15, row=(lane>>4)*4+reg
    #pragma unroll
    for (int mf = 0; mf < 2; ++mf)
        #pragma unroll
        for (int nf = 0; nf < 2; ++nf) {
            const int col = n0 + wn*32 + nf*16 + fr;
            const float bv = bias[col];
            #pragma unroll
            for (int r = 0; r < 4; ++r) {
                const int row = m0 + wm*32 + mf*16 + kg*4 + r;
                const float o = acc[mf][nf][r] + bv;
                const size_t idx = (size_t)row * DMODEL + col;
                if (MODE == 0) Cf[idx] = o;
                else           ((_Float16*)C0)[idx] = (_Float16)o;
            }
        }
}

// ---------------------------------------------------------------------------
// V transpose -> FRAGMENT-MAJOR layout: vtf[head][kb][d][ks] with k = kb*16+ks.
// ---------------------------------------------------------------------------
__global__ __launch_bounds__(256) void vtransf_kernel(
    const short* __restrict__ vh, short* __restrict__ vtf)
{
    __shared__ short T[64][72];
    const int tid = threadIdx.x;
    const int s  = blockIdx.y;          // head 0..31
    const int t0 = blockIdx.x * 64;     // l-tile (4 kb blocks)
    const size_t slab = (size_t)s * SLAB;

    {   // read 64 l-rows x 64 d (coalesced 32 B / thread)
        const int r = tid >> 2, c0 = (tid & 3) << 4;
        const short* src = vh + slab + (size_t)(t0 + r) * DHD + c0;
        short8 a = *(const short8*)src;
        short8 b = *(const short8*)(src + 8);
        *(short8*)&T[r][c0]     = a;
        *(short8*)&T[r][c0 + 8] = b;
    }
    __syncthreads();
    {   // write vtf[(kb*64 + d)*16 + ks] = T[kbl*16 + ks][d]  (32 B / thread)
        const int kbl = tid >> 6, d = tid & 63;
        short8 o0, o1;
        #pragma unroll
        for (int j = 0; j < 8; ++j) { o0[j] = T[kbl*16 + j][d]; o1[j] = T[kbl*16 + 8 + j][d]; }
        short* dst = vtf + slab + ((size_t)((t0 >> 4) + kbl) * 64 + d) * 16;
        *(short8*)dst       = o0;
        *(short8*)(dst + 8) = o1;
    }
}

// ---------------------------------------------------------------------------
// Attention, one WG (512 thr / 8 waves) per (bh, 16-row q-tile). Single pass.
// SWAPPED QK^T: mfma(K, Q) -> lane holds P[k=i*128+wv*16+kg*4+{0..3}][q=fr].
//   Phase 1: barrier-free per-wave K staging, 3-slot rotation (48 KB),
//            2-deep prefetch, counted vmcnt(4). Each STAGE is fenced with
//            sched_barrier(0)+lgkmcnt(0): HW-guarantees the slot's previous
//            ds_reads completed before the overwriting global_load_lds issues
//            (the r16 WAR race under 3-WG LDS contention).
//   Softmax: scalar per-lane m/li, 2 shfl_xor + small LDS combine.
//   Phase 2: r12's proven PV + NT-store loop; PB tile ALIASES dead KBuf.
//   Epilogue: 8-way k-slice reduce, also aliasing KBuf.
// LDS total ~48.8 KB -> 3 WGs/CU (24 waves, 75% occupancy; VGPR=64 allows it).
// ---------------------------------------------------------------------------
__global__ __launch_bounds__(512, 4) void attn_kernel(
    const _Float16* __restrict__ qf, const _Float16* __restrict__ kf,
    const _Float16* __restrict__ vtf,
    float* __restrict__ attn, float* __restrict__ ctx)
{
    __shared__ __align__(16) char KBuf[49152];   // 3 x 16 KB K slots; phase-2: PB; epilogue: partials
    __shared__ float redA[8][16];
    __shared__ float mrow[16], lirow[16];

    const int tid  = threadIdx.x;
    const int lane = tid & 63, wv = tid >> 6;
    const int fr = lane & 15, kg = lane >> 4;

    // head-major remap: all 128 q-tiles of head bh land on XCD (bh&7)
    const int wg  = blockIdx.x;
    const int rem = wg & 1023;
    const int q0  = (rem >> 3) << 4;               // q-tile * 16
    const int bh  = ((wg >> 10) << 3) + (rem & 7); // 0..31
    const size_t slab = (size_t)bh * SLAB;

    // Q fragments (B-operand: lane fr holds row q0+fr), replicated across waves
    half8 qa[2];
    #pragma unroll
    for (int ks = 0; ks < 2; ++ks)
        qa[ks] = *(const half8*)(qf + slab + (size_t)(q0 + fr) * DHD + ks*32 + kg*8);

    const int srow = lane >> 3;          // staging: row within 8-row block
    const int scb  = (lane & 7) ^ srow;  // pre-swizzled global 16B col-block

    f32x4 s[16];   // logit quads: k = i*128 + wv*16 + kg*4 + r,  q = q0 + fr

    // ---- Phase 1: QK^T (swapped), barrier-free per-wave 3-slot pipeline ----
    #define STAGE_K(TI, CUR) { \
        _Pragma("unroll") \
        for (int j = 0; j < 2; ++j) { \
            const int b = wv*2 + j; \
            GLOAD_LDS16(kf + slab + (size_t)((TI)*128 + b*8 + srow)*DHD + scb*8, \
                        KBuf + (CUR)*16384 + b*1024); \
        } }

    STAGE_K(0, 0);
    STAGE_K(1, 1);

    const int klo = (wv << 4) + fr;          // tile-local K row (wave-private range)
    const int sw  = fr & 7;                  // klo & 7
    #pragma unroll
    for (int i = 0; i < 16; ++i) {
        if (i + 2 < 16) {
            SCHEDB();              // pin: stage cannot hoist above prior reads/MFMAs
            LGKM0();               // HW guarantee: this wave's prior ds_reads complete
            STAGE_K(i + 2, (i + 2) % 3);
        }

        // wait for tile i only: allowed outstanding = 2*min(2, 15-i)
        if      (i <= 13) VMCNT4();
        else if (i == 14) VMCNT2();
        else              VMCNT0();

        const char* rp = KBuf + (i % 3)*16384 + (klo << 7);
        half8 kb0 = *(const half8*)(rp + ((kg ^ sw) << 4));
        half8 kb1 = *(const half8*)(rp + (((4 + kg) ^ sw) << 4));

        f32x4 a = {0.f,0.f,0.f,0.f};
        a = __builtin_amdgcn_mfma_f32_16x16x32_f16(kb0, qa[0], a, 0,0,0);  // SWAPPED
        a = __builtin_amdgcn_mfma_f32_16x16x32_f16(kb1, qa[1], a, 0,0,0);
        s[i] = a;
    }
    #undef STAGE_K

    // ---- softmax: all 4 quad comps share q = fr -> scalar m / li ----
    float m;
    {
        f32x4 mx = s[0];
        #pragma unroll
        for (int i = 1; i < 16; ++i) {
            mx.x = fmaxf(mx.x, s[i].x); mx.y = fmaxf(mx.y, s[i].y);
            mx.z = fmaxf(mx.z, s[i].z); mx.w = fmaxf(mx.w, s[i].w);
        }
        m = fmaxf(fmaxf(mx.x, mx.y), fmaxf(mx.z, mx.w));
        m = fmaxf(m, __shfl_xor(m, 16));
        m = fmaxf(m, __shfl_xor(m, 32));
    }
    if (lane < 16) redA[wv][lane] = m;
    __syncthreads();
    if (tid < 16) {
        float mm = redA[0][tid];
        #pragma unroll
        for (int w = 1; w < 8; ++w) mm = fmaxf(mm, redA[w][tid]);
        mrow[tid] = mm;
    }
    __syncthreads();
    m = mrow[fr];

    const float C = 8.0f * 1.44269504089f;   // SCALE=8 folded into log2e
    float sum = 0.f;
    #pragma unroll
    for (int i = 0; i < 16; ++i) {
        f32x4 p;
        p.x = exp2f((s[i].x - m) * C);
        p.y = exp2f((s[i].y - m) * C);
        p.z = exp2f((s[i].z - m) * C);
        p.w = exp2f((s[i].w - m) * C);
        s[i] = p;
        sum += (p.x + p.y) + (p.z + p.w);
    }
    sum += __shfl_xor(sum, 16);
    sum += __shfl_xor(sum, 32);
    if (lane < 16) redA[wv][lane] = sum;
    __syncthreads();
    if (tid < 16) {
        float l = 0.f;
        #pragma unroll
        for (int w = 0; w < 8; ++w) l += redA[w][tid];
        lirow[tid] = 1.0f / l;
    }
    __syncthreads();   // all waves done with KBuf K slots -> PB alias safe
    const float li = lirow[fr];

    // ---- Phase 2: PV (reg P + fragment-major V) + coalesced NT attn store ----
    // PB tile [2][16][136] f16 aliases KBuf (K slots dead after softmax).
    f32x4 acc[4];
    #pragma unroll
    for (int db = 0; db < 4; ++db) { f32x4 z = {0.f,0.f,0.f,0.f}; acc[db] = z; }

    _Float16* PBh = (_Float16*)KBuf;         // [2][16][136]
    const _Float16* vfb = vtf + slab;        // fragment-major V
    const int sq = tid >> 5, sc = tid & 31;  // store mapping: row q, 4-col chunk
    float* abase = attn + ((size_t)bh * LSEQ + q0 + sq) * LSEQ + (sc << 2);

    int cur = 0;
    #pragma unroll
    for (int t = 0; t < 16; ++t) {
        // normalized P quad (k = t*128 + wv*16 + kg*4 + r, q = fr)
        f32x4 p = s[t];
        p.x *= li; p.y *= li; p.z *= li; p.w *= li;
        h4_t pw = { (_Float16)p.x, (_Float16)p.y, (_Float16)p.z, (_Float16)p.w };

        // PB write for the store path (8 B contiguous per lane)
        *(h4_t*)&PBh[(size_t)cur*2176 + fr*136 + (wv << 4) + (kg << 2)] = pw;

        // PV: A-frag = 512 B contiguous wave load from vtf block kb = t*8+wv
        const _Float16* vb = vfb + ((size_t)(t*8 + wv) << 10) + (fr << 4) + (kg << 2);
        #pragma unroll
        for (int db = 0; db < 4; ++db) {
            h4_t va = *(const h4_t*)(vb + db*256);
            acc[db] = __builtin_amdgcn_mfma_f32_16x16x16f16(va, pw, acc[db], 0,0,0);
        }

        LGKM0();                   // PB writes landed
        BARRIER();                 // whole P tile ready

        // coalesced NON-TEMPORAL store: 16 rows x 512 B full lines, bypass L2
        h4_t pr = *(const h4_t*)&PBh[(size_t)cur*2176 + sq*136 + (sc << 2)];
        f4raw o = { (float)pr[0], (float)pr[1], (float)pr[2], (float)pr[3] };
        __builtin_nontemporal_store(o, (f4raw*)(abase + (size_t)t * 128));

        cur ^= 1;
    }

    // ---- epilogue: 8-way k-slice reduce (aliases KBuf, 32 KB) ----
    __syncthreads();
    {
        float* pt = (float*)KBuf;            // [8][16][64]
        #pragma unroll
        for (int db = 0; db < 4; ++db) {
            float4 o = { acc[db].x, acc[db].y, acc[db].z, acc[db].w };
            *(float4*)(pt + wv*1024 + fr*64 + db*16 + (kg << 2)) = o;
        }
    }
    __syncthreads();
    {
        float* pt = (float*)KBuf;
        const int e = tid << 1;              // 512 thr x 2 floats = 16x64
        const int q = e >> 6, d = e & 63;
        float2 r2 = {0.f, 0.f};
        #pragma unroll
        for (int w = 0; w < 8; ++w) {
            float2 t2 = *(float2*)(pt + w*1024 + q*64 + d);
            r2.x += t2.x; r2.y += t2.y;
        }
        *(float2*)(ctx + slab + (size_t)(q0 + q) * DHD + d) = r2;
    }
}

// ---------------------------------------------------------------------------
// Residual + LayerNorm: out = LN(resid + x) * gamma + beta, one row per block
// ---------------------------------------------------------------------------
__global__ __launch_bounds__(128) void ln_kernel(
    const float* __restrict__ resid, const float* __restrict__ x,
    const float* __restrict__ gamma, const float* __restrict__ beta,
    float* __restrict__ out)
{
    const int row = blockIdx.x;
    const int tid = threadIdx.x;
    const size_t base = (size_t)row * DMODEL + tid*4;

    float4 v = *(const float4*)(x + base);
    float4 rq = *(const float4*)(resid + base);
    v.x += rq.x; v.y += rq.y; v.z += rq.z; v.w += rq.w;

    float s  = v.x + v.y + v.z + v.w;
    float ss = v.x*v.x + v.y*v.y + v.z*v.z + v.w*v.w;
    #pragma unroll
    for (int d = 1; d < 64; d <<= 1) { s += __shfl_xor(s, d); ss += __shfl_xor(ss, d); }

    __shared__ float red[2][2];
    const int wv = tid >> 6;
    if ((tid & 63) == 0) { red[wv][0] = s; red[wv][1] = ss; }
    __syncthreads();
    s  = red[0][0] + red[1][0];
    ss = red[0][1] + red[1][1];

    const float mu  = s * (1.0f/512.0f);
    const float var = ss * (1.0f/512.0f) - mu*mu;
    const float rs  = rsqrtf(var + 1e-5f);

    float4 g = *(const float4*)(gamma + tid*4);
    float4 b = *(const float4*)(beta + tid*4);
    float4 o;
    o.x = (v.x - mu) * rs * g.x + b.x;
    o.y = (v.y - mu) * rs * g.y + b.y;
    o.z = (v.z - mu) * rs * g.z + b.z;
    o.w = (v.w - mu) * rs * g.w + b.w;
    *(float4*)(out + base) = o;
}

// ---------------------------------------------------------------------------
extern "C" void kernel_launch(void* const* d_in, const int* in_sizes, int n_in,
                              void* d_out, int out_size, void* d_ws, size_t ws_size,
                              hipStream_t stream)
{
    const float* query = (const float*)d_in[0];
    const float* key   = (const float*)d_in[1];
    const float* value = (const float*)d_in[2];
    const float* Wq = (const float*)d_in[3];
    const float* bq = (const float*)d_in[4];
    const float* Wk = (const float*)d_in[5];
    const float* bk = (const float*)d_in[6];
    const float* Wv = (const float*)d_in[7];
    const float* bv = (const float*)d_in[8];
    const float* Wo = (const float*)d_in[9];
    const float* bo = (const float*)d_in[10];
    const float* gamma = (const float*)d_in[11];
    const float* beta  = (const float*)d_in[12];

    float* out  = (float*)d_out;            // [B,L,D] = 4,194,304 f32
    float* attn = out + 4194304;            // [32,2048,2048] f32

    const size_t NTOK = (size_t)8192 * 512; // 4,194,304 elements
    short* qv = (short*)d_ws;               // f16 projected tensors
    short* kv = qv + NTOK;
    short* vf = kv + NTOK;
    short* vtf = vf + NTOK;                 // fragment-major V^T per head
    // obuf aliases qv/kv (dead after attn_kernel); ws requirement = 32 MB
    float* obuf = (float*)d_ws;

    dim3 pgrid(8, 128), pblk(256);
    proj_gemm<3><<<pgrid, pblk, 0, stream>>>(query, Wq, bq, nullptr, qv);
    proj_gemm<3><<<pgrid, pblk, 0, stream>>>(key,   Wk, bk, nullptr, kv);
    proj_gemm<3><<<pgrid, pblk, 0, stream>>>(value, Wv, bv, nullptr, vf);

    vtransf_kernel<<<dim3(32, 32), 256, 0, stream>>>(vf, vtf);

    attn_kernel<<<4096, 512, 0, stream>>>((const _Float16*)qv, (const _Float16*)kv,
                                          (const _Float16*)vtf, attn, out /*ctx*/);

    proj_gemm<0><<<pgrid, pblk, 0, stream>>>(out /*ctx*/, Wo, bo, obuf, nullptr);
    ln_kernel<<<8192, 128, 0, stream>>>(query, obuf, gamma, beta, out);
}

// Round 18
// 248.710 us; speedup vs baseline: 1.3657x; 1.1511x over previous
//
#include <hip/hip_runtime.h>

// Problem constants
#define LSEQ 2048
#define DMODEL 512
#define DHD 64          // head dim of the (faithful) raw view
#define SLAB (LSEQ*DHD) // 131072 elements per contiguous head slab

typedef __attribute__((ext_vector_type(8))) short short8;
typedef __attribute__((ext_vector_type(4))) short short4v;
typedef __attribute__((ext_vector_type(4))) float f32x4;
typedef float f4raw __attribute__((ext_vector_type(4)));   // raw clang vector (NT-store legal)
typedef _Float16 half8 __attribute__((ext_vector_type(8)));
typedef _Float16 h4_t  __attribute__((ext_vector_type(4)));

__device__ __forceinline__ short f2bf(float x) {   // round-to-nearest-even bf16
    union { float f; unsigned u; } v; v.f = x;
    unsigned r = v.u + 0x7FFF + ((v.u >> 16) & 1);
    return (short)(r >> 16);
}
__device__ __forceinline__ float bf2f(short h) {
    union { float f; unsigned u; } v; v.u = ((unsigned)(unsigned short)h) << 16;
    return v.f;
}

// direct global->LDS async copy, 16 B per lane (dest = wave-uniform base + lane*16)
#define GLOAD_LDS16(g, l) __builtin_amdgcn_global_load_lds( \
    (const __attribute__((address_space(1))) void*)(g),     \
    (__attribute__((address_space(3))) void*)(l), 16, 0, 0)

#define VMCNT0()  asm volatile("s_waitcnt vmcnt(0)" ::: "memory")
#define VMCNT2()  asm volatile("s_waitcnt vmcnt(2)" ::: "memory")
#define VMCNT4()  asm volatile("s_waitcnt vmcnt(4)" ::: "memory")
#define LGKM0()   asm volatile("s_waitcnt lgkmcnt(0)" ::: "memory")
#define SCHEDB()  __builtin_amdgcn_sched_barrier(0)
#define BARRIER() do { __builtin_amdgcn_s_barrier(); __builtin_amdgcn_sched_barrier(0); } while (0)

// ---------------------------------------------------------------------------
// convw: W[512][512] f32 -> FRAGMENT-MAJOR hi/lo bf16:
//   F[((nt*16+kt)*2+half)*512 + fr*32 + kg*8], n = nt*16+fr, k = kt*32+kg*8.
// A wave's B-fragment (cols nt*16+fr, k-slice kt) is then 1 KB contiguous.
// ---------------------------------------------------------------------------
__global__ __launch_bounds__(256) void convw_kernel(
    const float* __restrict__ W0, const float* __restrict__ W1,
    const float* __restrict__ W2, const float* __restrict__ W3,
    short* __restrict__ F0, short* __restrict__ F1,
    short* __restrict__ F2, short* __restrict__ F3)
{
    const int which = blockIdx.y;
    const float* W = which==0 ? W0 : which==1 ? W1 : which==2 ? W2 : W3;
    short*       F = which==0 ? F0 : which==1 ? F1 : which==2 ? F2 : F3;

    const int g  = blockIdx.x * 256 + threadIdx.x;  // 0..32767
    const int n  = g >> 6, kc = g & 63;             // row, 8-elem k-chunk
    const float* src = W + (size_t)n * 512 + kc * 8;
    float4 a0 = *(const float4*)src;
    float4 a1 = *(const float4*)(src + 4);
    float v[8] = {a0.x,a0.y,a0.z,a0.w,a1.x,a1.y,a1.z,a1.w};
    short8 h, l;
    #pragma unroll
    for (int j = 0; j < 8; ++j) { short hh = f2bf(v[j]); h[j] = hh; l[j] = f2bf(v[j] - bf2f(hh)); }

    const int nt = n >> 4, fr = n & 15, kt = kc >> 2, kg = kc & 3;
    short* dh = F + ((size_t)(nt*16 + kt) * 2) * 512 + fr*32 + kg*8;
    *(short8*)dh        = h;
    *(short8*)(dh + 512) = l;
}

// ---------------------------------------------------------------------------
// proj2: C[8192,512] = A @ W^T + bias, split-f32 (3 bf16 MFMAs).
// Tile 64 rows x 256 cols, 512 thr / 8 waves (wave wv owns cols wv*32..+32).
// Only A staged in LDS (converted in-kernel, 2x redundancy); W fragments
// pre-converted (convw) and loaded global->reg as 1 KB contiguous wave loads.
// blockIdx.z selects (A, F, bias, out) triple -> Q/K/V in ONE launch.
// MODE 3: f16 out.  MODE 0: f32 out.
// ---------------------------------------------------------------------------
template<int MODE>
__global__ __launch_bounds__(512) void proj2_kernel(
    const float* __restrict__ A0, const float* __restrict__ A1, const float* __restrict__ A2,
    const short* __restrict__ F0, const short* __restrict__ F1, const short* __restrict__ F2,
    const float* __restrict__ b0, const float* __restrict__ b1, const float* __restrict__ b2,
    float* __restrict__ Cf0, float* __restrict__ Cf1, float* __restrict__ Cf2,
    short* __restrict__ C00, short* __restrict__ C01, short* __restrict__ C02)
{
    __shared__ __align__(16) short Ah[64][40], Al[64][40];

    const int z = blockIdx.z;
    const float* A    = z==0 ? A0 : z==1 ? A1 : A2;
    const short* F    = z==0 ? F0 : z==1 ? F1 : F2;
    const float* bias = z==0 ? b0 : z==1 ? b1 : b2;
    float* Cf         = z==0 ? Cf0 : z==1 ? Cf1 : Cf2;
    short* C0         = z==0 ? C00 : z==1 ? C01 : C02;

    const int tid  = threadIdx.x;
    const int lane = tid & 63, wv = tid >> 6;
    const int fr = lane & 15, kg = lane >> 4;
    const int m0 = blockIdx.y * 64, n0 = blockIdx.x * 256;

    f32x4 acc[4][2];
    #pragma unroll
    for (int i = 0; i < 4; ++i)
        #pragma unroll
        for (int j = 0; j < 2; ++j) { f32x4 zo = {0.f,0.f,0.f,0.f}; acc[i][j] = zo; }

    const int srow = tid >> 3, sc4 = (tid & 7) << 2;   // 64 rows x 8 f32x4 chunks

    for (int kt = 0; kt < 16; ++kt) {
        __syncthreads();
        {   // stage A tile (64x32 f32 -> hi/lo bf16), 4 f32 per thread
            const float* ap = A + (size_t)(m0 + srow) * DMODEL + kt*32 + sc4;
            float4 a0 = *(const float4*)ap;
            float v[4] = {a0.x, a0.y, a0.z, a0.w};
            short4v h, l;
            #pragma unroll
            for (int j = 0; j < 4; ++j) { short hh = f2bf(v[j]); h[j] = hh; l[j] = f2bf(v[j] - bf2f(hh)); }
            *(short4v*)&Ah[srow][sc4] = h;
            *(short4v*)&Al[srow][sc4] = l;
        }
        __syncthreads();

        short8 ah[4], al[4];
        #pragma unroll
        for (int mf = 0; mf < 4; ++mf) {
            ah[mf] = *(short8*)&Ah[mf*16 + fr][kg*8];
            al[mf] = *(short8*)&Al[mf*16 + fr][kg*8];
        }
        #pragma unroll
        for (int nf = 0; nf < 2; ++nf) {
            const int nt = (n0 >> 4) + wv*2 + nf;
            const short* wf = F + ((size_t)(nt*16 + kt) * 2) * 512 + fr*32 + kg*8;
            short8 wh = *(const short8*)wf;
            short8 wl = *(const short8*)(wf + 512);
            #pragma unroll
            for (int mf = 0; mf < 4; ++mf) {
                acc[mf][nf] = __builtin_amdgcn_mfma_f32_16x16x32_bf16(ah[mf], wh, acc[mf][nf], 0,0,0);
                acc[mf][nf] = __builtin_amdgcn_mfma_f32_16x16x32_bf16(ah[mf], wl, acc[mf][nf], 0,0,0);
                acc[mf][nf] = __builtin_amdgcn_mfma_f32_16x16x32_bf16(al[mf], wh, acc[mf][nf], 0,0,0);
            }
        }
    }

    // epilogue: C/D layout col=fr, row=kg*4+r (within each 16x16 fragment)
    #pragma unroll
    for (int nf = 0; nf < 2; ++nf) {
        const int col = n0 + wv*32 + nf*16 + fr;
        const float bv = bias[col];
        #pragma unroll
        for (int mf = 0; mf < 4; ++mf) {
            #pragma unroll
            for (int r = 0; r < 4; ++r) {
                const int row = m0 + mf*16 + kg*4 + r;
                const float o = acc[mf][nf][r] + bv;
                const size_t idx = (size_t)row * DMODEL + col;
                if (MODE == 0) Cf[idx] = o;
                else           ((_Float16*)C0)[idx] = (_Float16)o;
            }
        }
    }
}

// ---------------------------------------------------------------------------
// V transpose -> FRAGMENT-MAJOR layout: vtf[head][kb][d][ks] with k = kb*16+ks.
// ---------------------------------------------------------------------------
__global__ __launch_bounds__(256) void vtransf_kernel(
    const short* __restrict__ vh, short* __restrict__ vtf)
{
    __shared__ short T[64][72];
    const int tid = threadIdx.x;
    const int s  = blockIdx.y;          // head 0..31
    const int t0 = blockIdx.x * 64;     // l-tile (4 kb blocks)
    const size_t slab = (size_t)s * SLAB;

    {   // read 64 l-rows x 64 d (coalesced 32 B / thread)
        const int r = tid >> 2, c0 = (tid & 3) << 4;
        const short* src = vh + slab + (size_t)(t0 + r) * DHD + c0;
        short8 a = *(const short8*)src;
        short8 b = *(const short8*)(src + 8);
        *(short8*)&T[r][c0]     = a;
        *(short8*)&T[r][c0 + 8] = b;
    }
    __syncthreads();
    {   // write vtf[(kb*64 + d)*16 + ks] = T[kbl*16 + ks][d]  (32 B / thread)
        const int kbl = tid >> 6, d = tid & 63;
        short8 o0, o1;
        #pragma unroll
        for (int j = 0; j < 8; ++j) { o0[j] = T[kbl*16 + j][d]; o1[j] = T[kbl*16 + 8 + j][d]; }
        short* dst = vtf + slab + ((size_t)((t0 >> 4) + kbl) * 64 + d) * 16;
        *(short8*)dst       = o0;
        *(short8*)(dst + 8) = o1;
    }
}

// ---------------------------------------------------------------------------
// Attention (r17, unchanged): one WG (512 thr / 8 waves) per (bh, q-tile).
// ---------------------------------------------------------------------------
__global__ __launch_bounds__(512, 4) void attn_kernel(
    const _Float16* __restrict__ qf, const _Float16* __restrict__ kf,
    const _Float16* __restrict__ vtf,
    float* __restrict__ attn, float* __restrict__ ctx)
{
    __shared__ __align__(16) char KBuf[49152];   // 3 x 16 KB K slots; phase-2: PB; epilogue: partials
    __shared__ float redA[8][16];
    __shared__ float mrow[16], lirow[16];

    const int tid  = threadIdx.x;
    const int lane = tid & 63, wv = tid >> 6;
    const int fr = lane & 15, kg = lane >> 4;

    // head-major remap: all 128 q-tiles of head bh land on XCD (bh&7)
    const int wg  = blockIdx.x;
    const int rem = wg & 1023;
    const int q0  = (rem >> 3) << 4;               // q-tile * 16
    const int bh  = ((wg >> 10) << 3) + (rem & 7); // 0..31
    const size_t slab = (size_t)bh * SLAB;

    // Q fragments (B-operand: lane fr holds row q0+fr), replicated across waves
    half8 qa[2];
    #pragma unroll
    for (int ks = 0; ks < 2; ++ks)
        qa[ks] = *(const half8*)(qf + slab + (size_t)(q0 + fr) * DHD + ks*32 + kg*8);

    const int srow = lane >> 3;          // staging: row within 8-row block
    const int scb  = (lane & 7) ^ srow;  // pre-swizzled global 16B col-block

    f32x4 s[16];   // logit quads: k = i*128 + wv*16 + kg*4 + r,  q = q0 + fr

    // ---- Phase 1: QK^T (swapped), barrier-free per-wave 3-slot pipeline ----
    #define STAGE_K(TI, CUR) { \
        _Pragma("unroll") \
        for (int j = 0; j < 2; ++j) { \
            const int b = wv*2 + j; \
            GLOAD_LDS16(kf + slab + (size_t)((TI)*128 + b*8 + srow)*DHD + scb*8, \
                        KBuf + (CUR)*16384 + b*1024); \
        } }

    STAGE_K(0, 0);
    STAGE_K(1, 1);

    const int klo = (wv << 4) + fr;          // tile-local K row (wave-private range)
    const int sw  = fr & 7;                  // klo & 7
    #pragma unroll
    for (int i = 0; i < 16; ++i) {
        if (i + 2 < 16) {
            SCHEDB();              // pin: stage cannot hoist above prior reads/MFMAs
            LGKM0();               // HW guarantee: this wave's prior ds_reads complete
            STAGE_K(i + 2, (i + 2) % 3);
        }

        // wait for tile i only: allowed outstanding = 2*min(2, 15-i)
        if      (i <= 13) VMCNT4();
        else if (i == 14) VMCNT2();
        else              VMCNT0();

        const char* rp = KBuf + (i % 3)*16384 + (klo << 7);
        half8 kb0 = *(const half8*)(rp + ((kg ^ sw) << 4));
        half8 kb1 = *(const half8*)(rp + (((4 + kg) ^ sw) << 4));

        f32x4 a = {0.f,0.f,0.f,0.f};
        a = __builtin_amdgcn_mfma_f32_16x16x32_f16(kb0, qa[0], a, 0,0,0);  // SWAPPED
        a = __builtin_amdgcn_mfma_f32_16x16x32_f16(kb1, qa[1], a, 0,0,0);
        s[i] = a;
    }
    #undef STAGE_K

    // ---- softmax: all 4 quad comps share q = fr -> scalar m / li ----
    float m;
    {
        f32x4 mx = s[0];
        #pragma unroll
        for (int i = 1; i < 16; ++i) {
            mx.x = fmaxf(mx.x, s[i].x); mx.y = fmaxf(mx.y, s[i].y);
            mx.z = fmaxf(mx.z, s[i].z); mx.w = fmaxf(mx.w, s[i].w);
        }
        m = fmaxf(fmaxf(mx.x, mx.y), fmaxf(mx.z, mx.w));
        m = fmaxf(m, __shfl_xor(m, 16));
        m = fmaxf(m, __shfl_xor(m, 32));
    }
    if (lane < 16) redA[wv][lane] = m;
    __syncthreads();
    if (tid < 16) {
        float mm = redA[0][tid];
        #pragma unroll
        for (int w = 1; w < 8; ++w) mm = fmaxf(mm, redA[w][tid]);
        mrow[tid] = mm;
    }
    __syncthreads();
    m = mrow[fr];

    const float C = 8.0f * 1.44269504089f;   // SCALE=8 folded into log2e
    float sum = 0.f;
    #pragma unroll
    for (int i = 0; i < 16; ++i) {
        f32x4 p;
        p.x = exp2f((s[i].x - m) * C);
        p.y = exp2f((s[i].y - m) * C);
        p.z = exp2f((s[i].z - m) * C);
        p.w = exp2f((s[i].w - m) * C);
        s[i] = p;
        sum += (p.x + p.y) + (p.z + p.w);
    }
    sum += __shfl_xor(sum, 16);
    sum += __shfl_xor(sum, 32);
    if (lane < 16) redA[wv][lane] = sum;
    __syncthreads();
    if (tid < 16) {
        float l = 0.f;
        #pragma unroll
        for (int w = 0; w < 8; ++w) l += redA[w][tid];
        lirow[tid] = 1.0f / l;
    }
    __syncthreads();   // all waves done with KBuf K slots -> PB alias safe
    const float li = lirow[fr];

    // ---- Phase 2: PV (reg P + fragment-major V) + coalesced NT attn store ----
    f32x4 acc[4];
    #pragma unroll
    for (int db = 0; db < 4; ++db) { f32x4 z = {0.f,0.f,0.f,0.f}; acc[db] = z; }

    _Float16* PBh = (_Float16*)KBuf;         // [2][16][136]
    const _Float16* vfb = vtf + slab;        // fragment-major V
    const int sq = tid >> 5, sc = tid & 31;  // store mapping: row q, 4-col chunk
    float* abase = attn + ((size_t)bh * LSEQ + q0 + sq) * LSEQ + (sc << 2);

    int cur = 0;
    #pragma unroll
    for (int t = 0; t < 16; ++t) {
        // normalized P quad (k = t*128 + wv*16 + kg*4 + r, q = fr)
        f32x4 p = s[t];
        p.x *= li; p.y *= li; p.z *= li; p.w *= li;
        h4_t pw = { (_Float16)p.x, (_Float16)p.y, (_Float16)p.z, (_Float16)p.w };

        // PB write for the store path (8 B contiguous per lane)
        *(h4_t*)&PBh[(size_t)cur*2176 + fr*136 + (wv << 4) + (kg << 2)] = pw;

        // PV: A-frag = 512 B contiguous wave load from vtf block kb = t*8+wv
        const _Float16* vb = vfb + ((size_t)(t*8 + wv) << 10) + (fr << 4) + (kg << 2);
        #pragma unroll
        for (int db = 0; db < 4; ++db) {
            h4_t va = *(const h4_t*)(vb + db*256);
            acc[db] = __builtin_amdgcn_mfma_f32_16x16x16f16(va, pw, acc[db], 0,0,0);
        }

        LGKM0();                   // PB writes landed
        BARRIER();                 // whole P tile ready

        // coalesced NON-TEMPORAL store: 16 rows x 512 B full lines, bypass L2
        h4_t pr = *(const h4_t*)&PBh[(size_t)cur*2176 + sq*136 + (sc << 2)];
        f4raw o = { (float)pr[0], (float)pr[1], (float)pr[2], (float)pr[3] };
        __builtin_nontemporal_store(o, (f4raw*)(abase + (size_t)t * 128));

        cur ^= 1;
    }

    // ---- epilogue: 8-way k-slice reduce (aliases KBuf, 32 KB) ----
    __syncthreads();
    {
        float* pt = (float*)KBuf;            // [8][16][64]
        #pragma unroll
        for (int db = 0; db < 4; ++db) {
            float4 o = { acc[db].x, acc[db].y, acc[db].z, acc[db].w };
            *(float4*)(pt + wv*1024 + fr*64 + db*16 + (kg << 2)) = o;
        }
    }
    __syncthreads();
    {
        float* pt = (float*)KBuf;
        const int e = tid << 1;              // 512 thr x 2 floats = 16x64
        const int q = e >> 6, d = e & 63;
        float2 r2 = {0.f, 0.f};
        #pragma unroll
        for (int w = 0; w < 8; ++w) {
            float2 t2 = *(float2*)(pt + w*1024 + q*64 + d);
            r2.x += t2.x; r2.y += t2.y;
        }
        *(float2*)(ctx + slab + (size_t)(q0 + q) * DHD + d) = r2;
    }
}

// ---------------------------------------------------------------------------
// Residual + LayerNorm: out = LN(resid + x) * gamma + beta, one row per block
// ---------------------------------------------------------------------------
__global__ __launch_bounds__(128) void ln_kernel(
    const float* __restrict__ resid, const float* __restrict__ x,
    const float* __restrict__ gamma, const float* __restrict__ beta,
    float* __restrict__ out)
{
    const int row = blockIdx.x;
    const int tid = threadIdx.x;
    const size_t base = (size_t)row * DMODEL + tid*4;

    float4 v = *(const float4*)(x + base);
    float4 rq = *(const float4*)(resid + base);
    v.x += rq.x; v.y += rq.y; v.z += rq.z; v.w += rq.w;

    float s  = v.x + v.y + v.z + v.w;
    float ss = v.x*v.x + v.y*v.y + v.z*v.z + v.w*v.w;
    #pragma unroll
    for (int d = 1; d < 64; d <<= 1) { s += __shfl_xor(s, d); ss += __shfl_xor(ss, d); }

    __shared__ float red[2][2];
    const int wv = tid >> 6;
    if ((tid & 63) == 0) { red[wv][0] = s; red[wv][1] = ss; }
    __syncthreads();
    s  = red[0][0] + red[1][0];
    ss = red[0][1] + red[1][1];

    const float mu  = s * (1.0f/512.0f);
    const float var = ss * (1.0f/512.0f) - mu*mu;
    const float rs  = rsqrtf(var + 1e-5f);

    float4 g = *(const float4*)(gamma + tid*4);
    float4 b = *(const float4*)(beta + tid*4);
    float4 o;
    o.x = (v.x - mu) * rs * g.x + b.x;
    o.y = (v.y - mu) * rs * g.y + b.y;
    o.z = (v.z - mu) * rs * g.z + b.z;
    o.w = (v.w - mu) * rs * g.w + b.w;
    *(float4*)(out + base) = o;
}

// ---------------------------------------------------------------------------
extern "C" void kernel_launch(void* const* d_in, const int* in_sizes, int n_in,
                              void* d_out, int out_size, void* d_ws, size_t ws_size,
                              hipStream_t stream)
{
    const float* query = (const float*)d_in[0];
    const float* key   = (const float*)d_in[1];
    const float* value = (const float*)d_in[2];
    const float* Wq = (const float*)d_in[3];
    const float* bq = (const float*)d_in[4];
    const float* Wk = (const float*)d_in[5];
    const float* bk = (const float*)d_in[6];
    const float* Wv = (const float*)d_in[7];
    const float* bv = (const float*)d_in[8];
    const float* Wo = (const float*)d_in[9];
    const float* bo = (const float*)d_in[10];
    const float* gamma = (const float*)d_in[11];
    const float* beta  = (const float*)d_in[12];

    float* out  = (float*)d_out;            // [B,L,D] = 4,194,304 f32
    float* attn = out + 4194304;            // [32,2048,2048] f32

    const size_t NTOK = (size_t)8192 * 512; // 4,194,304 elements
    short* qv = (short*)d_ws;               // f16 projected tensors
    short* kv = qv + NTOK;
    short* vf = kv + NTOK;
    short* vtf = vf + NTOK;                 // fragment-major V^T per head
    short* wfq = vtf + NTOK;                // fragment-major hi/lo weights (512 KB each)
    short* wfk = wfq + 524288;
    short* wfv = wfk + 524288;
    short* wfo = wfv + 524288;
    // obuf aliases qv/kv (dead after attn_kernel); ws requirement = 36 MB
    float* obuf = (float*)d_ws;

    convw_kernel<<<dim3(128, 4), 256, 0, stream>>>(Wq, Wk, Wv, Wo, wfq, wfk, wfv, wfo);

    proj2_kernel<3><<<dim3(2, 128, 3), 512, 0, stream>>>(
        query, key, value, wfq, wfk, wfv, bq, bk, bv,
        nullptr, nullptr, nullptr, qv, kv, vf);

    vtransf_kernel<<<dim3(32, 32), 256, 0, stream>>>(vf, vtf);

    attn_kernel<<<4096, 512, 0, stream>>>((const _Float16*)qv, (const _Float16*)kv,
                                          (const _Float16*)vtf, attn, out /*ctx*/);

    proj2_kernel<0><<<dim3(2, 128, 1), 512, 0, stream>>>(
        out /*ctx*/, out, out, wfo, wfo, wfo, bo, bo, bo,
        obuf, obuf, obuf, nullptr, nullptr, nullptr);

    ln_kernel<<<8192, 128, 0, stream>>>(query, obuf, gamma, beta, out);
}